// Round 10
// baseline (408.992 us; speedup 1.0000x reference)
//
#include <hip/hip_runtime.h>

typedef float f32x4 __attribute__((ext_vector_type(4)));
typedef short s16x8 __attribute__((ext_vector_type(8)));

#define MFMA16(A,B,C) __builtin_amdgcn_mfma_f32_16x16x32_bf16((A),(B),(C),0,0,0)

__device__ __forceinline__ short f2bf(float f) {
  union { float f; unsigned u; } v; v.f = f;
  unsigned r = v.u + 0x7FFFu + ((v.u >> 16) & 1u);   // RNE
  return (short)(r >> 16);
}

__device__ __forceinline__ void gload_lds16(const void* g, void* l) {
  __builtin_amdgcn_global_load_lds(
      (const __attribute__((address_space(1))) unsigned*)g,
      (__attribute__((address_space(3))) unsigned*)l, 16, 0, 0);
}

// ---------------- prep: transpose weights to bf16[N][K], gather bias table ----
__global__ __launch_bounds__(256) void prep_kernel(
    const float* __restrict__ Wqkv, const float* __restrict__ Wo,
    const float* __restrict__ posb, const int* __restrict__ relp,
    short* __restrict__ WqkvT, short* __restrict__ WoT, float* __restrict__ biasF)
{
  int i = blockIdx.x * 256 + threadIdx.x;
  if (i < 1152 * 384) {
    int n = i / 384, k = i % 384;
    WqkvT[i] = f2bf(Wqkv[k * 1152 + n]);
  } else if (i < 1152 * 384 + 384 * 384) {
    int j = i - 1152 * 384;
    int n = j / 384, k = j % 384;
    WoT[j] = f2bf(Wo[k * 384 + n]);
  } else {
    int j = i - (1152 * 384 + 384 * 384);    // j < 12*64*64 = 49152
    int h = j >> 12, qk = j & 4095;
    biasF[j] = posb[h * 16129 + relp[qk]];
  }
}

// ---------------- QKV GEMM fused with X f32->bf16 conversion ------------------
// X(100352x384 f32) @ WqkvT^T -> Q/K/Vt bf16. 128x128 tile, 4 waves, BK=64,
// 2-deep counted-vmcnt pipeline (R7-proven skeleton).
// A path (NEW): global f32 -> regs (issued at top of iter T for stage T+2,
// T14 async-split) -> f2bf -> ds_write_b128 at bottom (contiguous 1024B/wave
// per instr = conflict-free). B path: global_load_lds (unchanged).
// LDS layout per buffer: slot s of row holds global chunk s^(row&7) — same
// XOR involution as R7 on both fill and read (rule #21).
__global__ __launch_bounds__(256) void qkv_gemm(
    const float* __restrict__ X, const short* __restrict__ WqkvT,
    short* __restrict__ Qb, short* __restrict__ Kb, short* __restrict__ Vtb)
{
  __shared__ short lds[32768];   // buf sel: A @ sel*16384, B @ sel*16384+8192
  const int bid = blockIdx.x;
  const int wg = (bid & 7) * 882 + (bid >> 3);   // XCD swizzle (7056 = 8*882)
  const int nt = wg % 9, mt = wg / 9;
  const int t = threadIdx.x;
  const int wv = t >> 6, l = t & 63, lr = l & 15, lg = l >> 4;
  const int wm = wv >> 1, wn = wv & 1;

  f32x4 acc[4][4];
#pragma unroll
  for (int fm = 0; fm < 4; ++fm)
#pragma unroll
    for (int fn = 0; fn < 4; ++fn) acc[fm][fn] = (f32x4)0.0f;

  // staging geometry: instr i covers rows wv*32 + i*8 + (l>>3), slot l&7;
  // pre-swizzled global chunk cg = (l&7) ^ (row&7)  (row&7 const over i*8)
  const int srow = wv * 32 + (l >> 3);
  const int cg = (l & 7) ^ (srow & 7);
  const float* Axf = X     + (size_t)(mt * 128 + srow) * 384 + cg * 8;
  const short* Bb  = WqkvT + (size_t)(nt * 128 + srow) * 384 + cg * 8;
  // A ds_write dest (shorts): row*64 + (l&7)*8
  const int adst = srow * 64 + (l & 7) * 8;

  float4 ax[8], ay[8];

#define ALOAD(DST, KS) do {                                                  \
  _Pragma("unroll")                                                          \
  for (int i_ = 0; i_ < 4; ++i_) {                                           \
    const float* p_ = Axf + i_ * 8 * 384 + (KS) * 64;                        \
    DST[2*i_]   = *(const float4*)p_;                                        \
    DST[2*i_+1] = *(const float4*)(p_ + 4);                                  \
  } } while (0)

#define AWRITE(SRC, SEL) do {                                                \
  _Pragma("unroll")                                                          \
  for (int i_ = 0; i_ < 4; ++i_) {                                           \
    s16x8 pk_;                                                               \
    pk_[0] = f2bf(SRC[2*i_].x);   pk_[1] = f2bf(SRC[2*i_].y);                \
    pk_[2] = f2bf(SRC[2*i_].z);   pk_[3] = f2bf(SRC[2*i_].w);                \
    pk_[4] = f2bf(SRC[2*i_+1].x); pk_[5] = f2bf(SRC[2*i_+1].y);              \
    pk_[6] = f2bf(SRC[2*i_+1].z); pk_[7] = f2bf(SRC[2*i_+1].w);              \
    *(s16x8*)(lds + (SEL) * 16384 + adst + i_ * 512) = pk_;                  \
  } } while (0)

#define STAGE_B(KS, SEL) do {                                                \
  _Pragma("unroll")                                                          \
  for (int i_ = 0; i_ < 4; ++i_) {                                           \
    gload_lds16(Bb + i_ * 3072 + (KS) * 64,                                  \
                lds + (SEL) * 16384 + 8192 + (wv * 4 + i_) * 512);           \
  } } while (0)

#define COMPUTE(SEL) do {                                                    \
  const short* Acur_ = lds + (SEL) * 16384;                                  \
  const short* Bcur_ = Acur_ + 8192;                                         \
  _Pragma("unroll")                                                          \
  for (int kk = 0; kk < 2; ++kk) {                                           \
    s16x8 af[4], bf[4];                                                      \
    _Pragma("unroll")                                                        \
    for (int f = 0; f < 4; ++f) {                                            \
      const int arow = wm * 64 + f * 16 + lr;                                \
      const int ac = (kk * 4 + lg) ^ (arow & 7);                             \
      af[f] = *(const s16x8*)(Acur_ + arow * 64 + ac * 8);                   \
      const int brow = wn * 64 + f * 16 + lr;                                \
      const int bc = (kk * 4 + lg) ^ (brow & 7);                             \
      bf[f] = *(const s16x8*)(Bcur_ + brow * 64 + bc * 8);                   \
    }                                                                        \
    _Pragma("unroll")                                                        \
    for (int fm = 0; fm < 4; ++fm)                                           \
      _Pragma("unroll")                                                      \
      for (int fn = 0; fn < 4; ++fn)                                         \
        acc[fm][fn] = MFMA16(af[fm], bf[fn], acc[fm][fn]);                   \
  } } while (0)

  // ---- prologue: stages 0 and 1 ----
  ALOAD(ax, 0);                              // 8 vm
  ALOAD(ay, 1);                              // 16 vm
  STAGE_B(0, 0);                             // 20 vm
  STAGE_B(1, 1);                             // 24 vm
  asm volatile("s_waitcnt vmcnt(16)" ::: "memory");   // ax landed
  AWRITE(ax, 0);
  asm volatile("s_waitcnt vmcnt(8)" ::: "memory");    // ay landed (B0,B1 out)
  AWRITE(ay, 1);
  asm volatile("s_waitcnt lgkmcnt(0)" ::: "memory");  // our ds_writes visible

  // iter T: [top wait] barrier; ALOAD(T+2); COMPUTE(T); lgkm(0); barrier;
  //         STAGE_B(T+2); vmcnt(4); AWRITE(T+2)
#define ITER(T, TOPW) do {                                                   \
  TOPW;                                                                      \
  __builtin_amdgcn_s_barrier();                                              \
  if ((T) + 2 < 6) ALOAD(ax, (T) + 2);                                       \
  COMPUTE((T) & 1);                                                          \
  asm volatile("s_waitcnt lgkmcnt(0)" ::: "memory");  /* WAR drain */        \
  __builtin_amdgcn_s_barrier();                                              \
  if ((T) + 2 < 6) {                                                         \
    STAGE_B((T) + 2, (T) & 1);                                               \
    asm volatile("s_waitcnt vmcnt(4)" ::: "memory");  /* ax + older in */    \
    AWRITE(ax, (T) & 1);                                                     \
  } } while (0)

  ITER(0, asm volatile("s_waitcnt vmcnt(4)" ::: "memory"));
  ITER(1, );
  ITER(2, );
  ITER(3, );
  ITER(4, );
  ITER(5, asm volatile("s_waitcnt vmcnt(0)" ::: "memory"));
#undef ITER
#undef COMPUTE
#undef STAGE_B
#undef AWRITE
#undef ALOAD

  // ---- epilogue ----
  const int sel = nt / 3, hq = (nt % 3) * 4;
  if (sel == 2) {
    // V: direct transposed stores Vt[win][h][d][tok] (R3-proven path)
#pragma unroll
    for (int fm = 0; fm < 4; ++fm)
#pragma unroll
      for (int fn = 0; fn < 4; ++fn) {
        const int m0 = wm * 64 + fm * 16 + lg * 4;
        const int win = m0 >> 6, tok0 = m0 & 63;
        const int n = wn * 64 + fn * 16 + lr;
        const int hl = n >> 5, d = n & 31;
        short4 v;
        v.x = f2bf(acc[fm][fn][0]); v.y = f2bf(acc[fm][fn][1]);
        v.z = f2bf(acc[fm][fn][2]); v.w = f2bf(acc[fm][fn][3]);
        *(short4*)(Vtb + (size_t)(mt * 2 + win) * 24576 + (hq + hl) * 2048
                   + d * 64 + tok0) = v;
      }
  } else {
    // Q/K: re-stage tile in LDS (stride 138, bank-coprime), coalesced writes
    __syncthreads();                     // pipeline fully drained
    short* Cl = lds;                     // 128*138 = 17664 shorts, fits
#pragma unroll
    for (int fm = 0; fm < 4; ++fm)
#pragma unroll
      for (int fn = 0; fn < 4; ++fn)
#pragma unroll
        for (int r = 0; r < 4; ++r)
          Cl[(wm * 64 + fm * 16 + lg * 4 + r) * 138 + wn * 64 + fn * 16 + lr] =
              f2bf(acc[fm][fn][r]);
    __syncthreads();
    short* dst0 = (sel ? Kb : Qb) + (size_t)mt * 2 * 24576;
#pragma unroll
    for (int rr = 0; rr < 2; ++rr) {
      const int ro = t * 2 + rr;
      const int win = ro >> 8, hl = (ro >> 6) & 3, tok = ro & 63;
      const int m = win * 64 + tok;
      const short* srcl = Cl + m * 138 + hl * 32;
      int4 a0 = *(const int4*)(srcl);
      int4 a1 = *(const int4*)(srcl + 8);
      int4 a2 = *(const int4*)(srcl + 16);
      int4 a3 = *(const int4*)(srcl + 24);
      short* dp = dst0 + win * 24576 + (hq + hl) * 2048 + tok * 32;
      *(int4*)(dp)      = a0;
      *(int4*)(dp + 8)  = a1;
      *(int4*)(dp + 16) = a2;
      *(int4*)(dp + 24) = a3;
    }
  }
}

// ---------------- attention: one wave per (window, head) ----------------------
__global__ __launch_bounds__(256) void attn_split(
    const short* __restrict__ Qb, const short* __restrict__ Kb,
    const short* __restrict__ Vtb, const float* __restrict__ biasF,
    short* __restrict__ AO)
{
  __shared__ short obuf[10240];          // 4 waves * [64][40]
  const int bid = blockIdx.x;
  const int wg = (bid & 7) * 588 + (bid >> 3);   // XCD swizzle (4704 = 8*588)
  const int wv = threadIdx.x >> 6;
  const int l = threadIdx.x & 63, lr = l & 15, lg = l >> 4;
  const int p = wg * 4 + wv;                     // (w,h) pair, p = w*12 + h
  const int w = p / 12, h = p % 12;

  const short* Kp = Kb + (size_t)p * 2048;
  const short* Qp = Qb + (size_t)p * 2048;
  const short* Vp = Vtb + (size_t)p * 2048;
  const float* bh = biasF + h * 4096;

  s16x8 ka[4], qf[4];
#pragma unroll
  for (int f = 0; f < 4; ++f) {
    ka[f] = *(const s16x8*)(Kp + (f * 16 + lr) * 32 + lg * 8);
    qf[f] = *(const s16x8*)(Qp + (f * 16 + lr) * 32 + lg * 8);
  }
  s16x8 va[2][2];
#pragma unroll
  for (int fd = 0; fd < 2; ++fd)
#pragma unroll
    for (int kb = 0; kb < 2; ++kb) {
      short4 v0 = *(const short4*)(Vp + (fd * 16 + lr) * 64 + kb * 32 + lg * 4);
      short4 v1 = *(const short4*)(Vp + (fd * 16 + lr) * 64 + kb * 32 + 16 + lg * 4);
      s16x8 tv;
      tv[0] = v0.x; tv[1] = v0.y; tv[2] = v0.z; tv[3] = v0.w;
      tv[4] = v1.x; tv[5] = v1.y; tv[6] = v1.z; tv[7] = v1.w;
      va[fd][kb] = tv;
    }

  // S^T = K·Q^T  (rows kt, cols q), K-dim 32
  f32x4 st[4][4];
#pragma unroll
  for (int fk = 0; fk < 4; ++fk)
#pragma unroll
    for (int fq = 0; fq < 4; ++fq)
      st[fk][fq] = MFMA16(ka[fk], qf[fq], (f32x4)0.0f);

  // scale + bias + softmax over kt (per q column, per-lane + shfl 16/32)
#pragma unroll
  for (int fq = 0; fq < 4; ++fq) {
    const int q = fq * 16 + lr;
    float4 bv[4];
#pragma unroll
    for (int fk = 0; fk < 4; ++fk)
      bv[fk] = *(const float4*)(bh + q * 64 + fk * 16 + lg * 4);
    float mx = -3.0e38f;
#pragma unroll
    for (int fk = 0; fk < 4; ++fk)
#pragma unroll
      for (int r = 0; r < 4; ++r) {
        float v = st[fk][fq][r] * 0.17677669529663687f + ((const float*)&bv[fk])[r];
        st[fk][fq][r] = v;
        mx = fmaxf(mx, v);
      }
    mx = fmaxf(mx, __shfl_xor(mx, 16));
    mx = fmaxf(mx, __shfl_xor(mx, 32));
    float sm = 0.0f;
#pragma unroll
    for (int fk = 0; fk < 4; ++fk)
#pragma unroll
      for (int r = 0; r < 4; ++r) {
        float e = __expf(st[fk][fq][r] - mx);
        st[fk][fq][r] = e;
        sm += e;
      }
    sm += __shfl_xor(sm, 16);
    sm += __shfl_xor(sm, 32);
    const float inv = 1.0f / sm;
#pragma unroll
    for (int fk = 0; fk < 4; ++fk)
#pragma unroll
      for (int r = 0; r < 4; ++r) st[fk][fq][r] *= inv;
  }

  // O^T = V^T · P^T ; sigma(g,j)=32kb+16(j>>2)+4g+(j&3) on both operands
  f32x4 ot[2][4];
#pragma unroll
  for (int fd = 0; fd < 2; ++fd)
#pragma unroll
    for (int fq = 0; fq < 4; ++fq) ot[fd][fq] = (f32x4)0.0f;
#pragma unroll
  for (int kb = 0; kb < 2; ++kb)
#pragma unroll
    for (int fq = 0; fq < 4; ++fq) {
      s16x8 pb;
#pragma unroll
      for (int j = 0; j < 8; ++j)
        pb[j] = f2bf(st[2 * kb + (j >> 2)][fq][j & 3]);   // lane-local repack
#pragma unroll
      for (int fd = 0; fd < 2; ++fd)
        ot[fd][fq] = MFMA16(va[fd][kb], pb, ot[fd][fq]);
    }

  // epilogue: stage [q][d] per-wave in LDS, write coalesced 16B rows
  short* ob = obuf + wv * 2560;
#pragma unroll
  for (int fd = 0; fd < 2; ++fd)
#pragma unroll
    for (int fq = 0; fq < 4; ++fq)
#pragma unroll
      for (int r = 0; r < 4; ++r)
        ob[(fq * 16 + lr) * 40 + fd * 16 + lg * 4 + r] = f2bf(ot[fd][fq][r]);
  short* dst = AO + ((size_t)w * 64 + l) * 384 + h * 32;
  int4 o0 = *(const int4*)(ob + l * 40);
  int4 o1 = *(const int4*)(ob + l * 40 + 8);
  int4 o2 = *(const int4*)(ob + l * 40 + 16);
  int4 o3 = *(const int4*)(ob + l * 40 + 24);
  *(int4*)(dst)      = o0;
  *(int4*)(dst + 8)  = o1;
  *(int4*)(dst + 16) = o2;
  *(int4*)(dst + 24) = o3;
}

// ---------------- output projection: out = AO(bf16) @ Wo + bo, f32 out --------
// R7-proven BK=64 2-deep counted-vmcnt pipeline (reverted from R9's BK=32).
__global__ __launch_bounds__(256) void proj_kernel(
    const short* __restrict__ AO, const short* __restrict__ WoT,
    const float* __restrict__ bo, float* __restrict__ out)
{
  __shared__ short lds[32768];
  const int bid = blockIdx.x;
  const int wg = (bid & 7) * 294 + (bid >> 3);   // XCD swizzle (2352 = 8*294)
  const int nt = wg % 3, mt = wg / 3;
  const int t = threadIdx.x;
  const int wv = t >> 6, l = t & 63, lr = l & 15, lg = l >> 4;
  const int wm = wv >> 1, wn = wv & 1;

  f32x4 acc[4][4];
#pragma unroll
  for (int fm = 0; fm < 4; ++fm)
#pragma unroll
    for (int fn = 0; fn < 4; ++fn) acc[fm][fn] = (f32x4)0.0f;

  const int srow = wv * 32 + (l >> 3);
  const int cg = (l & 7) ^ (srow & 7);
  const short* Ab = AO  + (size_t)(mt * 128 + srow) * 384 + cg * 8;
  const short* Bb = WoT + (size_t)(nt * 128 + srow) * 384 + cg * 8;

#define STAGE(KS, SEL) do {                                                  \
  _Pragma("unroll")                                                          \
  for (int i_ = 0; i_ < 4; ++i_) {                                           \
    gload_lds16(Ab + i_ * 3072 + (KS) * 64,                                  \
                lds + (SEL) * 16384 + (wv * 4 + i_) * 512);                  \
    gload_lds16(Bb + i_ * 3072 + (KS) * 64,                                  \
                lds + (SEL) * 16384 + 8192 + (wv * 4 + i_) * 512);           \
  } } while (0)

#define COMPUTE(SEL) do {                                                    \
  const short* Acur_ = lds + (SEL) * 16384;                                  \
  const short* Bcur_ = Acur_ + 8192;                                         \
  _Pragma("unroll")                                                          \
  for (int kk = 0; kk < 2; ++kk) {                                           \
    s16x8 af[4], bf[4];                                                      \
    _Pragma("unroll")                                                        \
    for (int f = 0; f < 4; ++f) {                                            \
      const int arow = wm * 64 + f * 16 + lr;                                \
      const int ac = (kk * 4 + lg) ^ (arow & 7);                             \
      af[f] = *(const s16x8*)(Acur_ + arow * 64 + ac * 8);                   \
      const int brow = wn * 64 + f * 16 + lr;                                \
      const int bc = (kk * 4 + lg) ^ (brow & 7);                             \
      bf[f] = *(const s16x8*)(Bcur_ + brow * 64 + bc * 8);                   \
    }                                                                        \
    _Pragma("unroll")                                                        \
    for (int fm = 0; fm < 4; ++fm)                                           \
      _Pragma("unroll")                                                      \
      for (int fn = 0; fn < 4; ++fn)                                         \
        acc[fm][fn] = MFMA16(af[fm], bf[fn], acc[fm][fn]);                   \
  } } while (0)

#define ITER(T, WN) do {                                                     \
  asm volatile("s_waitcnt vmcnt(" #WN ")" ::: "memory");                     \
  __builtin_amdgcn_s_barrier();                                              \
  COMPUTE((T) & 1);                                                          \
  asm volatile("s_waitcnt lgkmcnt(0)" ::: "memory");  /* WAR drain */        \
  __builtin_amdgcn_s_barrier();                                              \
  if ((T) + 2 < 6) STAGE((T) + 2, (T) & 1);                                  \
  } while (0)

  STAGE(0, 0);
  STAGE(1, 1);
  ITER(0, 8); ITER(1, 8); ITER(2, 8); ITER(3, 8); ITER(4, 8); ITER(5, 0);
#undef ITER
#undef COMPUTE
#undef STAGE

#pragma unroll
  for (int fn = 0; fn < 4; ++fn) {
    const int n = nt * 128 + wn * 64 + fn * 16 + lr;
    const float bias = bo[n];
#pragma unroll
    for (int fm = 0; fm < 4; ++fm) {
      const int m0 = mt * 128 + wm * 64 + fm * 16 + lg * 4;
#pragma unroll
      for (int r = 0; r < 4; ++r)
        out[(size_t)(m0 + r) * 384 + n] = acc[fm][fn][r] + bias;
    }
  }
}

extern "C" void kernel_launch(void* const* d_in, const int* in_sizes, int n_in,
                              void* d_out, int out_size, void* d_ws, size_t ws_size,
                              hipStream_t stream)
{
  const float* X    = (const float*)d_in[0];
  const float* Wqkv = (const float*)d_in[1];
  const float* posb = (const float*)d_in[2];
  const float* Wo   = (const float*)d_in[3];
  const float* bo   = (const float*)d_in[4];
  const int*   relp = (const int*)d_in[5];
  float* out = (float*)d_out;

  // workspace carve — total 309,657,600 B (proven available)
  char* ws = (char*)d_ws;
  short* WqkvT = (short*)(ws);                 //   884,736 B
  short* WoT   = (short*)(ws + 884736);        //   294,912 B
  float* biasF = (float*)(ws + 1179648);       //   196,608 B
  short* AO    = (short*)(ws + 1376256);       // 77,070,336 B [100352][384]
  short* Qb    = (short*)(ws + 78446592);      // 77,070,336 B [win][12][64][32]
  short* Kb    = (short*)(ws + 155516928);     // 77,070,336 B [win][12][64][32]
  short* Vtb   = (short*)(ws + 232587264);     // 77,070,336 B [win][12][32][64]

  prep_kernel<<<2496, 256, 0, stream>>>(Wqkv, Wo, posb, relp, WqkvT, WoT, biasF);
  qkv_gemm<<<7056, 256, 0, stream>>>(X, WqkvT, Qb, Kb, Vtb);
  attn_split<<<4704, 256, 0, stream>>>(Qb, Kb, Vtb, biasF, AO);
  proj_kernel<<<2352, 256, 0, stream>>>(AO, WoT, bo, out);
}

// Round 11
// 266.107 us; speedup vs baseline: 1.5369x; 1.5369x over previous
//
#include <hip/hip_runtime.h>

typedef float f32x4 __attribute__((ext_vector_type(4)));
typedef short s16x8 __attribute__((ext_vector_type(8)));

#define MFMA16(A,B,C) __builtin_amdgcn_mfma_f32_16x16x32_bf16((A),(B),(C),0,0,0)

__device__ __forceinline__ short f2bf(float f) {
  union { float f; unsigned u; } v; v.f = f;
  unsigned r = v.u + 0x7FFFu + ((v.u >> 16) & 1u);   // RNE
  return (short)(r >> 16);
}

__device__ __forceinline__ void gload_lds16(const void* g, void* l) {
  __builtin_amdgcn_global_load_lds(
      (const __attribute__((address_space(1))) unsigned*)g,
      (__attribute__((address_space(3))) unsigned*)l, 16, 0, 0);
}

// ---------------- prep: transpose weights to bf16[N][K], gather bias table ----
__global__ __launch_bounds__(256) void prep_kernel(
    const float* __restrict__ Wqkv, const float* __restrict__ Wo,
    const float* __restrict__ posb, const int* __restrict__ relp,
    short* __restrict__ WqkvT, short* __restrict__ WoT, float* __restrict__ biasF)
{
  int i = blockIdx.x * 256 + threadIdx.x;
  if (i < 1152 * 384) {
    int n = i / 384, k = i % 384;
    WqkvT[i] = f2bf(Wqkv[k * 1152 + n]);
  } else if (i < 1152 * 384 + 384 * 384) {
    int j = i - 1152 * 384;
    int n = j / 384, k = j % 384;
    WoT[j] = f2bf(Wo[k * 384 + n]);
  } else {
    int j = i - (1152 * 384 + 384 * 384);    // j < 12*64*64 = 49152
    int h = j >> 12, qk = j & 4095;
    biasF[j] = posb[h * 16129 + relp[qk]];
  }
}

// ---------------- X f32 -> bf16 (memory-bound, vectorized) --------------------
__global__ __launch_bounds__(256) void xcvt_kernel(
    const float* __restrict__ X, short* __restrict__ Xbf)
{
  const int n8 = 4816896;                  // 38,535,168 / 8
  for (int i = blockIdx.x * 256 + threadIdx.x; i < n8; i += gridDim.x * 256) {
    float4 a = *(const float4*)(X + (size_t)i * 8);
    float4 b = *(const float4*)(X + (size_t)i * 8 + 4);
    s16x8 p;
    p[0] = f2bf(a.x); p[1] = f2bf(a.y); p[2] = f2bf(a.z); p[3] = f2bf(a.w);
    p[4] = f2bf(b.x); p[5] = f2bf(b.y); p[6] = f2bf(b.z); p[7] = f2bf(b.w);
    *(s16x8*)(Xbf + (size_t)i * 8) = p;
  }
}

// ---------------- fused QKV GEMM + attention ----------------------------------
// Grid 2352 = 784 mt x 3 head-groups. Block 512 thr / 8 waves (wm=wv>>2 win,
// wn=wv&3 head-local). GEMM: 128 tokens x 384 cols (q,k,v of 4 heads), BK=64,
// R7-proven 2-deep counted-vmcnt pipeline, both-sides XOR involution.
// B LDS rows ordered nlocal = head_local*96 + qkv*32 + d so wave (wm,wn) ends
// holding window (mt*2+wm), head (hg*4+wn)'s full QKV as acc[4][6] — exactly
// round-1's verified attn_fused layout; attn path is that code verbatim.
__global__ __launch_bounds__(512) void qkv_attn(
    const short* __restrict__ Xbf, const short* __restrict__ WqkvT,
    const float* __restrict__ biasF, short* __restrict__ AO)
{
  __shared__ short lds[65536];   // A: sel*8192 (16KB ea); B: 16384+sel*24576
  const int bid = blockIdx.x;
  const int wg = (bid & 7) * 294 + (bid >> 3);   // XCD swizzle (2352 = 8*294)
  const int hg = wg % 3, mt = wg / 3;
  const int t = threadIdx.x;
  const int wv = t >> 6, l = t & 63, lr = l & 15, lg = l >> 4;
  const int wm = wv >> 2, wn = wv & 3;

  f32x4 acc[4][6];
#pragma unroll
  for (int fm = 0; fm < 4; ++fm)
#pragma unroll
    for (int fn = 0; fn < 6; ++fn) acc[fm][fn] = (f32x4)0.0f;

  // staging geometry: per wave, instr i covers 8 rows (wv*16 + i*8 + (l>>3)),
  // slot l&7; global chunk = slot ^ (row&7) = (l&7)^(l>>3) (row&7 == l>>3)
  const int cgs = (l & 7) ^ (l >> 3);
  const short* AbT = Xbf + (size_t)(mt * 128 + wv * 16 + (l >> 3)) * 384 + cgs * 8;
  const short* BbT[3];
#pragma unroll
  for (int p = 0; p < 3; ++p)
    BbT[p] = WqkvT + (size_t)(p * 384 + hg * 128 + wv * 16 + (l >> 3)) * 384
             + cgs * 8;
  int boff[6];
#pragma unroll
  for (int p = 0; p < 3; ++p)
#pragma unroll
    for (int i = 0; i < 2; ++i) {
      const int j0 = wv * 16 + i * 8;
      boff[p * 2 + i] = (j0 >> 5) * 96 + p * 32 + (j0 & 31);   // nlocal base
    }

#define STAGE(KS, SEL) do {                                                  \
  _Pragma("unroll")                                                          \
  for (int i_ = 0; i_ < 2; ++i_)                                             \
    gload_lds16(AbT + i_ * 3072 + (KS) * 64,                                 \
                lds + (SEL) * 8192 + wv * 1024 + i_ * 512);                  \
  _Pragma("unroll")                                                          \
  for (int p_ = 0; p_ < 3; ++p_)                                             \
    _Pragma("unroll")                                                        \
    for (int i_ = 0; i_ < 2; ++i_)                                           \
      gload_lds16(BbT[p_] + i_ * 3072 + (KS) * 64,                           \
                  lds + 16384 + (SEL) * 24576 + boff[p_ * 2 + i_] * 64);     \
  } while (0)

#define COMPUTE(SEL) do {                                                    \
  const short* Acur_ = lds + (SEL) * 8192;                                   \
  const short* Bcur_ = lds + 16384 + (SEL) * 24576;                          \
  _Pragma("unroll")                                                          \
  for (int kk = 0; kk < 2; ++kk) {                                           \
    s16x8 af[4], bq[6];                                                      \
    _Pragma("unroll")                                                        \
    for (int f = 0; f < 4; ++f) {                                            \
      const int arow = wm * 64 + f * 16 + lr;                                \
      const int ac = (kk * 4 + lg) ^ (arow & 7);                             \
      af[f] = *(const s16x8*)(Acur_ + arow * 64 + ac * 8);                   \
    }                                                                        \
    _Pragma("unroll")                                                        \
    for (int fn = 0; fn < 6; ++fn) {                                         \
      const int brow = wn * 96 + fn * 16 + lr;                               \
      const int bc = (kk * 4 + lg) ^ (brow & 7);                             \
      bq[fn] = *(const s16x8*)(Bcur_ + brow * 64 + bc * 8);                  \
    }                                                                        \
    _Pragma("unroll")                                                        \
    for (int fm = 0; fm < 4; ++fm)                                           \
      _Pragma("unroll")                                                      \
      for (int fn = 0; fn < 6; ++fn)                                         \
        acc[fm][fn] = MFMA16(af[fm], bq[fn], acc[fm][fn]);                   \
  } } while (0)

#define ITER(T, WN) do {                                                     \
  asm volatile("s_waitcnt vmcnt(" #WN ")" ::: "memory");                     \
  __builtin_amdgcn_s_barrier();                                              \
  COMPUTE((T) & 1);                                                          \
  asm volatile("s_waitcnt lgkmcnt(0)" ::: "memory");  /* WAR drain */        \
  __builtin_amdgcn_s_barrier();                                              \
  if ((T) + 2 < 6) STAGE((T) + 2, (T) & 1);                                  \
  } while (0)

  STAGE(0, 0);
  STAGE(1, 1);
  ITER(0, 8); ITER(1, 8); ITER(2, 8); ITER(3, 8); ITER(4, 8); ITER(5, 0);
#undef ITER
#undef COMPUTE
#undef STAGE

  __syncthreads();       // GEMM LDS dead; reuse for per-wave attn scratch

  // ---- attention (round-1 verified path, one (window, head) per wave) ----
  const int w = mt * 2 + wm, h = hg * 4 + wn;
  short* Qs  = lds + wv * 7424;          // [64][40]
  short* Ks  = Qs + 2560;                // [64][40]
  short* Vts = Ks + 2560;                // [32][72]

  // scatter acc -> Q, K, V^T (fn: 0,1=Q 2,3=K 4,5=V; col d=(fn&1)*16+lr)
#pragma unroll
  for (int fm = 0; fm < 4; ++fm) {
#pragma unroll
    for (int fn = 0; fn < 6; ++fn) {
      const int sel = fn >> 1;
      const int d = (fn & 1) * 16 + lr;
      if (sel < 2) {
        short* dst = (sel ? Ks : Qs) + (fm * 16 + lg * 4) * 40 + d;
#pragma unroll
        for (int r = 0; r < 4; ++r) dst[r * 40] = f2bf(acc[fm][fn][r]);
      } else {                           // V stored transposed [d][tok]
        short4 v;
        v.x = f2bf(acc[fm][fn][0]); v.y = f2bf(acc[fm][fn][1]);
        v.z = f2bf(acc[fm][fn][2]); v.w = f2bf(acc[fm][fn][3]);
        *(short4*)(Vts + d * 72 + fm * 16 + lg * 4) = v;
      }
    }
  }

  // S^T = K·Q^T  (rows kt, cols q), K-dim 32
  s16x8 ka[4], qf[4];
#pragma unroll
  for (int f = 0; f < 4; ++f) {
    ka[f] = *(const s16x8*)(Ks + (f * 16 + lr) * 40 + lg * 8);
    qf[f] = *(const s16x8*)(Qs + (f * 16 + lr) * 40 + lg * 8);
  }
  f32x4 st[4][4];
#pragma unroll
  for (int fk = 0; fk < 4; ++fk)
#pragma unroll
    for (int fq = 0; fq < 4; ++fq)
      st[fk][fq] = MFMA16(ka[fk], qf[fq], (f32x4)0.0f);

  // scale + bias + softmax over kt (per q column, per-lane + shfl 16/32)
  const float* bh = biasF + h * 4096;
#pragma unroll
  for (int fq = 0; fq < 4; ++fq) {
    const int q = fq * 16 + lr;
    float4 bv[4];
#pragma unroll
    for (int fk = 0; fk < 4; ++fk)
      bv[fk] = *(const float4*)(bh + q * 64 + fk * 16 + lg * 4);
    float mx = -3.0e38f;
#pragma unroll
    for (int fk = 0; fk < 4; ++fk)
#pragma unroll
      for (int r = 0; r < 4; ++r) {
        float v = st[fk][fq][r] * 0.17677669529663687f + ((const float*)&bv[fk])[r];
        st[fk][fq][r] = v;
        mx = fmaxf(mx, v);
      }
    mx = fmaxf(mx, __shfl_xor(mx, 16));
    mx = fmaxf(mx, __shfl_xor(mx, 32));
    float sm = 0.0f;
#pragma unroll
    for (int fk = 0; fk < 4; ++fk)
#pragma unroll
      for (int r = 0; r < 4; ++r) {
        float e = __expf(st[fk][fq][r] - mx);
        st[fk][fq][r] = e;
        sm += e;
      }
    sm += __shfl_xor(sm, 16);
    sm += __shfl_xor(sm, 32);
    const float inv = 1.0f / sm;
#pragma unroll
    for (int fk = 0; fk < 4; ++fk)
#pragma unroll
      for (int r = 0; r < 4; ++r) st[fk][fq][r] *= inv;
  }

  // O^T = V^T · P^T ; sigma(g,j)=32kb+16(j>>2)+4g+(j&3) on both operands
  s16x8 va[2][2];
#pragma unroll
  for (int fd = 0; fd < 2; ++fd)
#pragma unroll
    for (int kb = 0; kb < 2; ++kb) {
      short4 v0 = *(const short4*)(Vts + (fd * 16 + lr) * 72 + kb * 32 + lg * 4);
      short4 v1 = *(const short4*)(Vts + (fd * 16 + lr) * 72 + kb * 32 + 16 + lg * 4);
      s16x8 tv;
      tv[0] = v0.x; tv[1] = v0.y; tv[2] = v0.z; tv[3] = v0.w;
      tv[4] = v1.x; tv[5] = v1.y; tv[6] = v1.z; tv[7] = v1.w;
      va[fd][kb] = tv;
    }
  f32x4 ot[2][4];
#pragma unroll
  for (int fd = 0; fd < 2; ++fd)
#pragma unroll
    for (int fq = 0; fq < 4; ++fq) ot[fd][fq] = (f32x4)0.0f;
#pragma unroll
  for (int kb = 0; kb < 2; ++kb)
#pragma unroll
    for (int fq = 0; fq < 4; ++fq) {
      s16x8 pb;
#pragma unroll
      for (int j = 0; j < 8; ++j)
        pb[j] = f2bf(st[2 * kb + (j >> 2)][fq][j & 3]);   // lane-local repack
#pragma unroll
      for (int fd = 0; fd < 2; ++fd)
        ot[fd][fq] = MFMA16(va[fd][kb], pb, ot[fd][fq]);
    }

  // epilogue: stage O [q][d] in Qs (dead), write coalesced 64B rows
#pragma unroll
  for (int fd = 0; fd < 2; ++fd)
#pragma unroll
    for (int fq = 0; fq < 4; ++fq)
#pragma unroll
      for (int r = 0; r < 4; ++r)
        Qs[(fq * 16 + lr) * 40 + fd * 16 + lg * 4 + r] = f2bf(ot[fd][fq][r]);
  short* dst = AO + ((size_t)w * 64 + l) * 384 + h * 32;
  int4 o0 = *(const int4*)(Qs + l * 40);
  int4 o1 = *(const int4*)(Qs + l * 40 + 8);
  int4 o2 = *(const int4*)(Qs + l * 40 + 16);
  int4 o3 = *(const int4*)(Qs + l * 40 + 24);
  *(int4*)(dst)      = o0;
  *(int4*)(dst + 8)  = o1;
  *(int4*)(dst + 16) = o2;
  *(int4*)(dst + 24) = o3;
}

// ---------------- output projection: out = AO(bf16) @ Wo + bo, f32 out --------
// R7-proven BK=64 2-deep counted-vmcnt pipeline.
__global__ __launch_bounds__(256) void proj_kernel(
    const short* __restrict__ AO, const short* __restrict__ WoT,
    const float* __restrict__ bo, float* __restrict__ out)
{
  __shared__ short lds[32768];
  const int bid = blockIdx.x;
  const int wg = (bid & 7) * 294 + (bid >> 3);   // XCD swizzle (2352 = 8*294)
  const int nt = wg % 3, mt = wg / 3;
  const int t = threadIdx.x;
  const int wv = t >> 6, l = t & 63, lr = l & 15, lg = l >> 4;
  const int wm = wv >> 1, wn = wv & 1;

  f32x4 acc[4][4];
#pragma unroll
  for (int fm = 0; fm < 4; ++fm)
#pragma unroll
    for (int fn = 0; fn < 4; ++fn) acc[fm][fn] = (f32x4)0.0f;

  const int srow = wv * 32 + (l >> 3);
  const int cg = (l & 7) ^ (srow & 7);
  const short* Ab = AO  + (size_t)(mt * 128 + srow) * 384 + cg * 8;
  const short* Bb = WoT + (size_t)(nt * 128 + srow) * 384 + cg * 8;

#define STAGE(KS, SEL) do {                                                  \
  _Pragma("unroll")                                                          \
  for (int i_ = 0; i_ < 4; ++i_) {                                           \
    gload_lds16(Ab + i_ * 3072 + (KS) * 64,                                  \
                lds + (SEL) * 16384 + (wv * 4 + i_) * 512);                  \
    gload_lds16(Bb + i_ * 3072 + (KS) * 64,                                  \
                lds + (SEL) * 16384 + 8192 + (wv * 4 + i_) * 512);           \
  } } while (0)

#define COMPUTE(SEL) do {                                                    \
  const short* Acur_ = lds + (SEL) * 16384;                                  \
  const short* Bcur_ = Acur_ + 8192;                                         \
  _Pragma("unroll")                                                          \
  for (int kk = 0; kk < 2; ++kk) {                                           \
    s16x8 af[4], bf[4];                                                      \
    _Pragma("unroll")                                                        \
    for (int f = 0; f < 4; ++f) {                                            \
      const int arow = wm * 64 + f * 16 + lr;                                \
      const int ac = (kk * 4 + lg) ^ (arow & 7);                             \
      af[f] = *(const s16x8*)(Acur_ + arow * 64 + ac * 8);                   \
      const int brow = wn * 64 + f * 16 + lr;                                \
      const int bc = (kk * 4 + lg) ^ (brow & 7);                             \
      bf[f] = *(const s16x8*)(Bcur_ + brow * 64 + bc * 8);                   \
    }                                                                        \
    _Pragma("unroll")                                                        \
    for (int fm = 0; fm < 4; ++fm)                                           \
      _Pragma("unroll")                                                      \
      for (int fn = 0; fn < 4; ++fn)                                         \
        acc[fm][fn] = MFMA16(af[fm], bf[fn], acc[fm][fn]);                   \
  } } while (0)

#define ITER(T, WN) do {                                                     \
  asm volatile("s_waitcnt vmcnt(" #WN ")" ::: "memory");                     \
  __builtin_amdgcn_s_barrier();                                              \
  COMPUTE((T) & 1);                                                          \
  asm volatile("s_waitcnt lgkmcnt(0)" ::: "memory");  /* WAR drain */        \
  __builtin_amdgcn_s_barrier();                                              \
  if ((T) + 2 < 6) STAGE((T) + 2, (T) & 1);                                  \
  } while (0)

  STAGE(0, 0);
  STAGE(1, 1);
  ITER(0, 8); ITER(1, 8); ITER(2, 8); ITER(3, 8); ITER(4, 8); ITER(5, 0);
#undef ITER
#undef COMPUTE
#undef STAGE

#pragma unroll
  for (int fn = 0; fn < 4; ++fn) {
    const int n = nt * 128 + wn * 64 + fn * 16 + lr;
    const float bias = bo[n];
#pragma unroll
    for (int fm = 0; fm < 4; ++fm) {
      const int m0 = mt * 128 + wm * 64 + fm * 16 + lg * 4;
#pragma unroll
      for (int r = 0; r < 4; ++r)
        out[(size_t)(m0 + r) * 384 + n] = acc[fm][fn][r] + bias;
    }
  }
}

extern "C" void kernel_launch(void* const* d_in, const int* in_sizes, int n_in,
                              void* d_out, int out_size, void* d_ws, size_t ws_size,
                              hipStream_t stream)
{
  const float* X    = (const float*)d_in[0];
  const float* Wqkv = (const float*)d_in[1];
  const float* posb = (const float*)d_in[2];
  const float* Wo   = (const float*)d_in[3];
  const float* bo   = (const float*)d_in[4];
  const int*   relp = (const int*)d_in[5];
  float* out = (float*)d_out;

  // workspace carve — ~155.5 MB (well under the 310 MB proven available)
  char* ws = (char*)d_ws;
  short* WqkvT = (short*)(ws);                 //   884,736 B
  short* WoT   = (short*)(ws + 884736);        //   294,912 B
  float* biasF = (float*)(ws + 1179648);       //   196,608 B
  short* Xbf   = (short*)(ws + 1376256);       // 77,070,336 B [100352][384]
  short* AO    = (short*)(ws + 78446592);      // 77,070,336 B [100352][384]

  prep_kernel<<<2496, 256, 0, stream>>>(Wqkv, Wo, posb, relp, WqkvT, WoT, biasF);
  xcvt_kernel<<<2048, 256, 0, stream>>>(X, Xbf);
  qkv_attn<<<2352, 512, 0, stream>>>(Xbf, WqkvT, biasF, AO);
  proj_kernel<<<2352, 256, 0, stream>>>(AO, WoT, bo, out);
}

// Round 12
// 243.689 us; speedup vs baseline: 1.6783x; 1.0920x over previous
//
#include <hip/hip_runtime.h>

typedef float f32x4 __attribute__((ext_vector_type(4)));
typedef short s16x8 __attribute__((ext_vector_type(8)));

#define MFMA16(A,B,C) __builtin_amdgcn_mfma_f32_16x16x32_bf16((A),(B),(C),0,0,0)

__device__ __forceinline__ short f2bf(float f) {
  union { float f; unsigned u; } v; v.f = f;
  unsigned r = v.u + 0x7FFFu + ((v.u >> 16) & 1u);   // RNE
  return (short)(r >> 16);
}

__device__ __forceinline__ void gload_lds16(const void* g, void* l) {
  __builtin_amdgcn_global_load_lds(
      (const __attribute__((address_space(1))) unsigned*)g,
      (__attribute__((address_space(3))) unsigned*)l, 16, 0, 0);
}

// ---------------- prep: transpose weights to bf16[N][K], gather bias table ----
__global__ __launch_bounds__(256) void prep_kernel(
    const float* __restrict__ Wqkv, const float* __restrict__ Wo,
    const float* __restrict__ posb, const int* __restrict__ relp,
    short* __restrict__ WqkvT, short* __restrict__ WoT, float* __restrict__ biasF)
{
  int i = blockIdx.x * 256 + threadIdx.x;
  if (i < 1152 * 384) {
    int n = i / 384, k = i % 384;
    WqkvT[i] = f2bf(Wqkv[k * 1152 + n]);
  } else if (i < 1152 * 384 + 384 * 384) {
    int j = i - 1152 * 384;
    int n = j / 384, k = j % 384;
    WoT[j] = f2bf(Wo[k * 384 + n]);
  } else {
    int j = i - (1152 * 384 + 384 * 384);    // j < 12*64*64 = 49152
    int h = j >> 12, qk = j & 4095;
    biasF[j] = posb[h * 16129 + relp[qk]];
  }
}

// ---------------- X f32 -> bf16 (memory-bound, vectorized) --------------------
__global__ __launch_bounds__(256) void xcvt_kernel(
    const float* __restrict__ X, short* __restrict__ Xbf)
{
  const int n8 = 4816896;                  // 38,535,168 / 8
  for (int i = blockIdx.x * 256 + threadIdx.x; i < n8; i += gridDim.x * 256) {
    float4 a = *(const float4*)(X + (size_t)i * 8);
    float4 b = *(const float4*)(X + (size_t)i * 8 + 4);
    s16x8 p;
    p[0] = f2bf(a.x); p[1] = f2bf(a.y); p[2] = f2bf(a.z); p[3] = f2bf(a.w);
    p[4] = f2bf(b.x); p[5] = f2bf(b.y); p[6] = f2bf(b.z); p[7] = f2bf(b.w);
    *(s16x8*)(Xbf + (size_t)i * 8) = p;
  }
}

// ---------------- fused QKV GEMM + attention (2 heads / block) ----------------
// Grid 4704 = 784 mt x 6 head-groups. Block 256 thr / 4 waves: wm=wv>>1 (win),
// wn=wv&1 (head_local). GEMM: 128 tokens x 192 cols (q,k,v of 2 heads), BK=64.
// LDS = A dbuf 32KB + B dbuf 48KB = 80KB -> 2 blocks/CU (R11 was 128KB -> 1);
// one block's attn VALU phase overlaps the other's GEMM MFMA phase.
// B LDS rows: nlocal = head_local*96 + qkv*32 + d. Same R7/R11-proven 2-deep
// counted-vmcnt ITER (10 loads/stage -> vmcnt(10)), lgkm WAR drain,
// both-sides XOR involution (slot s of row r holds global chunk s^(r&7)).
__global__ __launch_bounds__(256) void qkv_attn(
    const short* __restrict__ Xbf, const short* __restrict__ WqkvT,
    const float* __restrict__ biasF, short* __restrict__ AO)
{
  __shared__ short lds[40960];   // A: sel*8192 | B: 16384 + sel*12288 (shorts)
  const int bid = blockIdx.x;
  const int wg = (bid & 7) * 588 + (bid >> 3);   // XCD swizzle (4704 = 8*588)
  const int hg = wg % 6, mt = wg / 6;
  const int t = threadIdx.x;
  const int wv = t >> 6, l = t & 63, lr = l & 15, lg = l >> 4;
  const int wm = wv >> 1, wn = wv & 1;

  f32x4 acc[4][6];
#pragma unroll
  for (int fm = 0; fm < 4; ++fm)
#pragma unroll
    for (int fn = 0; fn < 6; ++fn) acc[fm][fn] = (f32x4)0.0f;

  // global chunk for staging lane: slot l&7, row-in-8 l>>3
  const int cgs = (l & 7) ^ (l >> 3);
  // A: instr i (0..3) covers token rows wv*32 + i*8 + (l>>3)
  const short* AbT = Xbf + (size_t)(mt * 128 + wv * 32 + (l >> 3)) * 384 + cgs * 8;
  // B: instr j (0..5) covers nlocal rows wv*48 + j*8 + (l>>3);
  // nlocal = head_local*96 + p*32 + d  ->  src row = p*384 + hg*64 + hl*32 + d
  const short* BbT[6];
#pragma unroll
  for (int j = 0; j < 6; ++j) {
    const int n0 = wv * 48 + j * 8 + (l >> 3);
    const int hl = n0 / 96, rem = n0 % 96;
    const int p = rem >> 5, d = rem & 31;
    BbT[j] = WqkvT + (size_t)(p * 384 + hg * 64 + hl * 32 + d) * 384 + cgs * 8;
  }

#define STAGE(KS, SEL) do {                                                  \
  _Pragma("unroll")                                                          \
  for (int i_ = 0; i_ < 4; ++i_)                                             \
    gload_lds16(AbT + i_ * 3072 + (KS) * 64,                                 \
                lds + (SEL) * 8192 + (wv * 4 + i_) * 512);                   \
  _Pragma("unroll")                                                          \
  for (int j_ = 0; j_ < 6; ++j_)                                             \
    gload_lds16(BbT[j_] + (KS) * 64,                                         \
                lds + 16384 + (SEL) * 12288 + (wv * 6 + j_) * 512);          \
  } while (0)

#define COMPUTE(SEL) do {                                                    \
  const short* Acur_ = lds + (SEL) * 8192;                                   \
  const short* Bcur_ = lds + 16384 + (SEL) * 12288;                          \
  _Pragma("unroll")                                                          \
  for (int kk = 0; kk < 2; ++kk) {                                           \
    s16x8 af[4], bq[6];                                                      \
    _Pragma("unroll")                                                        \
    for (int f = 0; f < 4; ++f) {                                            \
      const int arow = wm * 64 + f * 16 + lr;                                \
      const int ac = (kk * 4 + lg) ^ (arow & 7);                             \
      af[f] = *(const s16x8*)(Acur_ + arow * 64 + ac * 8);                   \
    }                                                                        \
    _Pragma("unroll")                                                        \
    for (int fn = 0; fn < 6; ++fn) {                                         \
      const int brow = wn * 96 + fn * 16 + lr;                               \
      const int bc = (kk * 4 + lg) ^ (brow & 7);                             \
      bq[fn] = *(const s16x8*)(Bcur_ + brow * 64 + bc * 8);                  \
    }                                                                        \
    _Pragma("unroll")                                                        \
    for (int fm = 0; fm < 4; ++fm)                                           \
      _Pragma("unroll")                                                      \
      for (int fn = 0; fn < 6; ++fn)                                         \
        acc[fm][fn] = MFMA16(af[fm], bq[fn], acc[fm][fn]);                   \
  } } while (0)

#define ITER(T, WN) do {                                                     \
  asm volatile("s_waitcnt vmcnt(" #WN ")" ::: "memory");                     \
  __builtin_amdgcn_s_barrier();                                              \
  COMPUTE((T) & 1);                                                          \
  asm volatile("s_waitcnt lgkmcnt(0)" ::: "memory");  /* WAR drain */        \
  __builtin_amdgcn_s_barrier();                                              \
  if ((T) + 2 < 6) STAGE((T) + 2, (T) & 1);                                  \
  } while (0)

  STAGE(0, 0);
  STAGE(1, 1);
  ITER(0, 10); ITER(1, 10); ITER(2, 10); ITER(3, 10); ITER(4, 10); ITER(5, 0);
#undef ITER
#undef COMPUTE
#undef STAGE

  __syncthreads();       // GEMM LDS dead; reuse for per-wave attn scratch

  // ---- attention (R1/R11-verified path, one (window, head) per wave) ----
  const int w = mt * 2 + wm, h = hg * 2 + wn;
  short* Qs  = lds + wv * 7424;          // [64][40]
  short* Ks  = Qs + 2560;                // [64][40]
  short* Vts = Ks + 2560;                // [32][72]

  // scatter acc -> Q, K, V^T (fn: 0,1=Q 2,3=K 4,5=V; col d=(fn&1)*16+lr)
#pragma unroll
  for (int fm = 0; fm < 4; ++fm) {
#pragma unroll
    for (int fn = 0; fn < 6; ++fn) {
      const int sel = fn >> 1;
      const int d = (fn & 1) * 16 + lr;
      if (sel < 2) {
        short* dst = (sel ? Ks : Qs) + (fm * 16 + lg * 4) * 40 + d;
#pragma unroll
        for (int r = 0; r < 4; ++r) dst[r * 40] = f2bf(acc[fm][fn][r]);
      } else {                           // V stored transposed [d][tok]
        short4 v;
        v.x = f2bf(acc[fm][fn][0]); v.y = f2bf(acc[fm][fn][1]);
        v.z = f2bf(acc[fm][fn][2]); v.w = f2bf(acc[fm][fn][3]);
        *(short4*)(Vts + d * 72 + fm * 16 + lg * 4) = v;
      }
    }
  }

  // S^T = K·Q^T  (rows kt, cols q), K-dim 32
  s16x8 ka[4], qf[4];
#pragma unroll
  for (int f = 0; f < 4; ++f) {
    ka[f] = *(const s16x8*)(Ks + (f * 16 + lr) * 40 + lg * 8);
    qf[f] = *(const s16x8*)(Qs + (f * 16 + lr) * 40 + lg * 8);
  }
  f32x4 st[4][4];
#pragma unroll
  for (int fk = 0; fk < 4; ++fk)
#pragma unroll
    for (int fq = 0; fq < 4; ++fq)
      st[fk][fq] = MFMA16(ka[fk], qf[fq], (f32x4)0.0f);

  // scale + bias + softmax over kt (per q column, per-lane + shfl 16/32)
  const float* bh = biasF + h * 4096;
#pragma unroll
  for (int fq = 0; fq < 4; ++fq) {
    const int q = fq * 16 + lr;
    float4 bv[4];
#pragma unroll
    for (int fk = 0; fk < 4; ++fk)
      bv[fk] = *(const float4*)(bh + q * 64 + fk * 16 + lg * 4);
    float mx = -3.0e38f;
#pragma unroll
    for (int fk = 0; fk < 4; ++fk)
#pragma unroll
      for (int r = 0; r < 4; ++r) {
        float v = st[fk][fq][r] * 0.17677669529663687f + ((const float*)&bv[fk])[r];
        st[fk][fq][r] = v;
        mx = fmaxf(mx, v);
      }
    mx = fmaxf(mx, __shfl_xor(mx, 16));
    mx = fmaxf(mx, __shfl_xor(mx, 32));
    float sm = 0.0f;
#pragma unroll
    for (int fk = 0; fk < 4; ++fk)
#pragma unroll
      for (int r = 0; r < 4; ++r) {
        float e = __expf(st[fk][fq][r] - mx);
        st[fk][fq][r] = e;
        sm += e;
      }
    sm += __shfl_xor(sm, 16);
    sm += __shfl_xor(sm, 32);
    const float inv = 1.0f / sm;
#pragma unroll
    for (int fk = 0; fk < 4; ++fk)
#pragma unroll
      for (int r = 0; r < 4; ++r) st[fk][fq][r] *= inv;
  }

  // O^T = V^T · P^T ; sigma(g,j)=32kb+16(j>>2)+4g+(j&3) on both operands
  s16x8 va[2][2];
#pragma unroll
  for (int fd = 0; fd < 2; ++fd)
#pragma unroll
    for (int kb = 0; kb < 2; ++kb) {
      short4 v0 = *(const short4*)(Vts + (fd * 16 + lr) * 72 + kb * 32 + lg * 4);
      short4 v1 = *(const short4*)(Vts + (fd * 16 + lr) * 72 + kb * 32 + 16 + lg * 4);
      s16x8 tv;
      tv[0] = v0.x; tv[1] = v0.y; tv[2] = v0.z; tv[3] = v0.w;
      tv[4] = v1.x; tv[5] = v1.y; tv[6] = v1.z; tv[7] = v1.w;
      va[fd][kb] = tv;
    }
  f32x4 ot[2][4];
#pragma unroll
  for (int fd = 0; fd < 2; ++fd)
#pragma unroll
    for (int fq = 0; fq < 4; ++fq) ot[fd][fq] = (f32x4)0.0f;
#pragma unroll
  for (int kb = 0; kb < 2; ++kb)
#pragma unroll
    for (int fq = 0; fq < 4; ++fq) {
      s16x8 pb;
#pragma unroll
      for (int j = 0; j < 8; ++j)
        pb[j] = f2bf(st[2 * kb + (j >> 2)][fq][j & 3]);   // lane-local repack
#pragma unroll
      for (int fd = 0; fd < 2; ++fd)
        ot[fd][fq] = MFMA16(va[fd][kb], pb, ot[fd][fq]);
    }

  // epilogue: stage O [q][d] in Qs (dead), write coalesced 64B rows
#pragma unroll
  for (int fd = 0; fd < 2; ++fd)
#pragma unroll
    for (int fq = 0; fq < 4; ++fq)
#pragma unroll
      for (int r = 0; r < 4; ++r)
        Qs[(fq * 16 + lr) * 40 + fd * 16 + lg * 4 + r] = f2bf(ot[fd][fq][r]);
  short* dst = AO + ((size_t)w * 64 + l) * 384 + h * 32;
  int4 o0 = *(const int4*)(Qs + l * 40);
  int4 o1 = *(const int4*)(Qs + l * 40 + 8);
  int4 o2 = *(const int4*)(Qs + l * 40 + 16);
  int4 o3 = *(const int4*)(Qs + l * 40 + 24);
  *(int4*)(dst)      = o0;
  *(int4*)(dst + 8)  = o1;
  *(int4*)(dst + 16) = o2;
  *(int4*)(dst + 24) = o3;
}

// ---------------- output projection: out = AO(bf16) @ Wo + bo, f32 out --------
// R7-proven BK=64 2-deep counted-vmcnt pipeline.
__global__ __launch_bounds__(256) void proj_kernel(
    const short* __restrict__ AO, const short* __restrict__ WoT,
    const float* __restrict__ bo, float* __restrict__ out)
{
  __shared__ short lds[32768];
  const int bid = blockIdx.x;
  const int wg = (bid & 7) * 294 + (bid >> 3);   // XCD swizzle (2352 = 8*294)
  const int nt = wg % 3, mt = wg / 3;
  const int t = threadIdx.x;
  const int wv = t >> 6, l = t & 63, lr = l & 15, lg = l >> 4;
  const int wm = wv >> 1, wn = wv & 1;

  f32x4 acc[4][4];
#pragma unroll
  for (int fm = 0; fm < 4; ++fm)
#pragma unroll
    for (int fn = 0; fn < 4; ++fn) acc[fm][fn] = (f32x4)0.0f;

  const int srow = wv * 32 + (l >> 3);
  const int cg = (l & 7) ^ (srow & 7);
  const short* Ab = AO  + (size_t)(mt * 128 + srow) * 384 + cg * 8;
  const short* Bb = WoT + (size_t)(nt * 128 + srow) * 384 + cg * 8;

#define STAGE(KS, SEL) do {                                                  \
  _Pragma("unroll")                                                          \
  for (int i_ = 0; i_ < 4; ++i_) {                                           \
    gload_lds16(Ab + i_ * 3072 + (KS) * 64,                                  \
                lds + (SEL) * 16384 + (wv * 4 + i_) * 512);                  \
    gload_lds16(Bb + i_ * 3072 + (KS) * 64,                                  \
                lds + (SEL) * 16384 + 8192 + (wv * 4 + i_) * 512);           \
  } } while (0)

#define COMPUTE(SEL) do {                                                    \
  const short* Acur_ = lds + (SEL) * 16384;                                  \
  const short* Bcur_ = Acur_ + 8192;                                         \
  _Pragma("unroll")                                                          \
  for (int kk = 0; kk < 2; ++kk) {                                           \
    s16x8 af[4], bf[4];                                                      \
    _Pragma("unroll")                                                        \
    for (int f = 0; f < 4; ++f) {                                            \
      const int arow = wm * 64 + f * 16 + lr;                                \
      const int ac = (kk * 4 + lg) ^ (arow & 7);                             \
      af[f] = *(const s16x8*)(Acur_ + arow * 64 + ac * 8);                   \
      const int brow = wn * 64 + f * 16 + lr;                                \
      const int bc = (kk * 4 + lg) ^ (brow & 7);                             \
      bf[f] = *(const s16x8*)(Bcur_ + brow * 64 + bc * 8);                   \
    }                                                                        \
    _Pragma("unroll")                                                        \
    for (int fm = 0; fm < 4; ++fm)                                           \
      _Pragma("unroll")                                                      \
      for (int fn = 0; fn < 4; ++fn)                                         \
        acc[fm][fn] = MFMA16(af[fm], bf[fn], acc[fm][fn]);                   \
  } } while (0)

#define ITER(T, WN) do {                                                     \
  asm volatile("s_waitcnt vmcnt(" #WN ")" ::: "memory");                     \
  __builtin_amdgcn_s_barrier();                                              \
  COMPUTE((T) & 1);                                                          \
  asm volatile("s_waitcnt lgkmcnt(0)" ::: "memory");  /* WAR drain */        \
  __builtin_amdgcn_s_barrier();                                              \
  if ((T) + 2 < 6) STAGE((T) + 2, (T) & 1);                                  \
  } while (0)

  STAGE(0, 0);
  STAGE(1, 1);
  ITER(0, 8); ITER(1, 8); ITER(2, 8); ITER(3, 8); ITER(4, 8); ITER(5, 0);
#undef ITER
#undef COMPUTE
#undef STAGE

#pragma unroll
  for (int fn = 0; fn < 4; ++fn) {
    const int n = nt * 128 + wn * 64 + fn * 16 + lr;
    const float bias = bo[n];
#pragma unroll
    for (int fm = 0; fm < 4; ++fm) {
      const int m0 = mt * 128 + wm * 64 + fm * 16 + lg * 4;
#pragma unroll
      for (int r = 0; r < 4; ++r)
        out[(size_t)(m0 + r) * 384 + n] = acc[fm][fn][r] + bias;
    }
  }
}

extern "C" void kernel_launch(void* const* d_in, const int* in_sizes, int n_in,
                              void* d_out, int out_size, void* d_ws, size_t ws_size,
                              hipStream_t stream)
{
  const float* X    = (const float*)d_in[0];
  const float* Wqkv = (const float*)d_in[1];
  const float* posb = (const float*)d_in[2];
  const float* Wo   = (const float*)d_in[3];
  const float* bo   = (const float*)d_in[4];
  const int*   relp = (const int*)d_in[5];
  float* out = (float*)d_out;

  // workspace carve — ~155.5 MB
  char* ws = (char*)d_ws;
  short* WqkvT = (short*)(ws);                 //   884,736 B
  short* WoT   = (short*)(ws + 884736);        //   294,912 B
  float* biasF = (float*)(ws + 1179648);       //   196,608 B
  short* Xbf   = (short*)(ws + 1376256);       // 77,070,336 B [100352][384]
  short* AO    = (short*)(ws + 78446592);      // 77,070,336 B [100352][384]

  prep_kernel<<<2496, 256, 0, stream>>>(Wqkv, Wo, posb, relp, WqkvT, WoT, biasF);
  xcvt_kernel<<<2048, 256, 0, stream>>>(X, Xbf);
  qkv_attn<<<4704, 256, 0, stream>>>(Xbf, WqkvT, biasF, AO);
  proj_kernel<<<2352, 256, 0, stream>>>(AO, WoT, bo, out);
}

// Round 13
// 235.358 us; speedup vs baseline: 1.7377x; 1.0354x over previous
//
#include <hip/hip_runtime.h>
#include <hip/hip_bf16.h>

typedef float f32x4 __attribute__((ext_vector_type(4)));
typedef short s16x8 __attribute__((ext_vector_type(8)));

#define MFMA16(A,B,C) __builtin_amdgcn_mfma_f32_16x16x32_bf16((A),(B),(C),0,0,0)

// Hardware RNE f32->bf16 (compiler emits v_cvt_pk_bf16_f32 for pairs; the
// old 4-5-op bit-twiddle was ~40% of qkv_attn's VALU budget). Same rounding.
__device__ __forceinline__ short f2bf(float f) {
  return (short)__bfloat16_as_ushort(__float2bfloat16(f));
}

__device__ __forceinline__ void gload_lds16(const void* g, void* l) {
  __builtin_amdgcn_global_load_lds(
      (const __attribute__((address_space(1))) unsigned*)g,
      (__attribute__((address_space(3))) unsigned*)l, 16, 0, 0);
}

// ---------------- prep: transpose weights to bf16[N][K], gather bias table ----
__global__ __launch_bounds__(256) void prep_kernel(
    const float* __restrict__ Wqkv, const float* __restrict__ Wo,
    const float* __restrict__ posb, const int* __restrict__ relp,
    short* __restrict__ WqkvT, short* __restrict__ WoT, float* __restrict__ biasF)
{
  int i = blockIdx.x * 256 + threadIdx.x;
  if (i < 1152 * 384) {
    int n = i / 384, k = i % 384;
    WqkvT[i] = f2bf(Wqkv[k * 1152 + n]);
  } else if (i < 1152 * 384 + 384 * 384) {
    int j = i - 1152 * 384;
    int n = j / 384, k = j % 384;
    WoT[j] = f2bf(Wo[k * 384 + n]);
  } else {
    int j = i - (1152 * 384 + 384 * 384);    // j < 12*64*64 = 49152
    int h = j >> 12, qk = j & 4095;
    biasF[j] = posb[h * 16129 + relp[qk]];
  }
}

// ---------------- X f32 -> bf16 (memory-bound, vectorized) --------------------
__global__ __launch_bounds__(256) void xcvt_kernel(
    const float* __restrict__ X, short* __restrict__ Xbf)
{
  const int n8 = 4816896;                  // 38,535,168 / 8
  for (int i = blockIdx.x * 256 + threadIdx.x; i < n8; i += gridDim.x * 256) {
    float4 a = *(const float4*)(X + (size_t)i * 8);
    float4 b = *(const float4*)(X + (size_t)i * 8 + 4);
    s16x8 p;
    p[0] = f2bf(a.x); p[1] = f2bf(a.y); p[2] = f2bf(a.z); p[3] = f2bf(a.w);
    p[4] = f2bf(b.x); p[5] = f2bf(b.y); p[6] = f2bf(b.z); p[7] = f2bf(b.w);
    *(s16x8*)(Xbf + (size_t)i * 8) = p;
  }
}

// ---------------- fused QKV GEMM + attention (2 heads / block) ----------------
// R12-proven structure, unchanged except f2bf -> hardware cvt.
__global__ __launch_bounds__(256) void qkv_attn(
    const short* __restrict__ Xbf, const short* __restrict__ WqkvT,
    const float* __restrict__ biasF, short* __restrict__ AO)
{
  __shared__ short lds[40960];   // A: sel*8192 | B: 16384 + sel*12288 (shorts)
  const int bid = blockIdx.x;
  const int wg = (bid & 7) * 588 + (bid >> 3);   // XCD swizzle (4704 = 8*588)
  const int hg = wg % 6, mt = wg / 6;
  const int t = threadIdx.x;
  const int wv = t >> 6, l = t & 63, lr = l & 15, lg = l >> 4;
  const int wm = wv >> 1, wn = wv & 1;

  f32x4 acc[4][6];
#pragma unroll
  for (int fm = 0; fm < 4; ++fm)
#pragma unroll
    for (int fn = 0; fn < 6; ++fn) acc[fm][fn] = (f32x4)0.0f;

  const int cgs = (l & 7) ^ (l >> 3);
  const short* AbT = Xbf + (size_t)(mt * 128 + wv * 32 + (l >> 3)) * 384 + cgs * 8;
  const short* BbT[6];
#pragma unroll
  for (int j = 0; j < 6; ++j) {
    const int n0 = wv * 48 + j * 8 + (l >> 3);
    const int hl = n0 / 96, rem = n0 % 96;
    const int p = rem >> 5, d = rem & 31;
    BbT[j] = WqkvT + (size_t)(p * 384 + hg * 64 + hl * 32 + d) * 384 + cgs * 8;
  }

#define STAGE(KS, SEL) do {                                                  \
  _Pragma("unroll")                                                          \
  for (int i_ = 0; i_ < 4; ++i_)                                             \
    gload_lds16(AbT + i_ * 3072 + (KS) * 64,                                 \
                lds + (SEL) * 8192 + (wv * 4 + i_) * 512);                   \
  _Pragma("unroll")                                                          \
  for (int j_ = 0; j_ < 6; ++j_)                                             \
    gload_lds16(BbT[j_] + (KS) * 64,                                         \
                lds + 16384 + (SEL) * 12288 + (wv * 6 + j_) * 512);          \
  } while (0)

#define COMPUTE(SEL) do {                                                    \
  const short* Acur_ = lds + (SEL) * 8192;                                   \
  const short* Bcur_ = lds + 16384 + (SEL) * 12288;                          \
  _Pragma("unroll")                                                          \
  for (int kk = 0; kk < 2; ++kk) {                                           \
    s16x8 af[4], bq[6];                                                      \
    _Pragma("unroll")                                                        \
    for (int f = 0; f < 4; ++f) {                                            \
      const int arow = wm * 64 + f * 16 + lr;                                \
      const int ac = (kk * 4 + lg) ^ (arow & 7);                             \
      af[f] = *(const s16x8*)(Acur_ + arow * 64 + ac * 8);                   \
    }                                                                        \
    _Pragma("unroll")                                                        \
    for (int fn = 0; fn < 6; ++fn) {                                         \
      const int brow = wn * 96 + fn * 16 + lr;                               \
      const int bc = (kk * 4 + lg) ^ (brow & 7);                             \
      bq[fn] = *(const s16x8*)(Bcur_ + brow * 64 + bc * 8);                  \
    }                                                                        \
    _Pragma("unroll")                                                        \
    for (int fm = 0; fm < 4; ++fm)                                           \
      _Pragma("unroll")                                                      \
      for (int fn = 0; fn < 6; ++fn)                                         \
        acc[fm][fn] = MFMA16(af[fm], bq[fn], acc[fm][fn]);                   \
  } } while (0)

#define ITER(T, WN) do {                                                     \
  asm volatile("s_waitcnt vmcnt(" #WN ")" ::: "memory");                     \
  __builtin_amdgcn_s_barrier();                                              \
  COMPUTE((T) & 1);                                                          \
  asm volatile("s_waitcnt lgkmcnt(0)" ::: "memory");  /* WAR drain */        \
  __builtin_amdgcn_s_barrier();                                              \
  if ((T) + 2 < 6) STAGE((T) + 2, (T) & 1);                                  \
  } while (0)

  STAGE(0, 0);
  STAGE(1, 1);
  ITER(0, 10); ITER(1, 10); ITER(2, 10); ITER(3, 10); ITER(4, 10); ITER(5, 0);
#undef ITER
#undef COMPUTE
#undef STAGE

  __syncthreads();       // GEMM LDS dead; reuse for per-wave attn scratch

  // ---- attention (R1/R11-verified path, one (window, head) per wave) ----
  const int w = mt * 2 + wm, h = hg * 2 + wn;
  short* Qs  = lds + wv * 7424;          // [64][40]
  short* Ks  = Qs + 2560;                // [64][40]
  short* Vts = Ks + 2560;                // [32][72]

  // scatter acc -> Q, K, V^T (fn: 0,1=Q 2,3=K 4,5=V; col d=(fn&1)*16+lr)
#pragma unroll
  for (int fm = 0; fm < 4; ++fm) {
#pragma unroll
    for (int fn = 0; fn < 6; ++fn) {
      const int sel = fn >> 1;
      const int d = (fn & 1) * 16 + lr;
      if (sel < 2) {
        short* dst = (sel ? Ks : Qs) + (fm * 16 + lg * 4) * 40 + d;
#pragma unroll
        for (int r = 0; r < 4; ++r) dst[r * 40] = f2bf(acc[fm][fn][r]);
      } else {                           // V stored transposed [d][tok]
        short4 v;
        v.x = f2bf(acc[fm][fn][0]); v.y = f2bf(acc[fm][fn][1]);
        v.z = f2bf(acc[fm][fn][2]); v.w = f2bf(acc[fm][fn][3]);
        *(short4*)(Vts + d * 72 + fm * 16 + lg * 4) = v;
      }
    }
  }

  // S^T = K·Q^T  (rows kt, cols q), K-dim 32
  s16x8 ka[4], qf[4];
#pragma unroll
  for (int f = 0; f < 4; ++f) {
    ka[f] = *(const s16x8*)(Ks + (f * 16 + lr) * 40 + lg * 8);
    qf[f] = *(const s16x8*)(Qs + (f * 16 + lr) * 40 + lg * 8);
  }
  f32x4 st[4][4];
#pragma unroll
  for (int fk = 0; fk < 4; ++fk)
#pragma unroll
    for (int fq = 0; fq < 4; ++fq)
      st[fk][fq] = MFMA16(ka[fk], qf[fq], (f32x4)0.0f);

  // scale + bias + softmax over kt (per q column, per-lane + shfl 16/32)
  const float* bh = biasF + h * 4096;
#pragma unroll
  for (int fq = 0; fq < 4; ++fq) {
    const int q = fq * 16 + lr;
    float4 bv[4];
#pragma unroll
    for (int fk = 0; fk < 4; ++fk)
      bv[fk] = *(const float4*)(bh + q * 64 + fk * 16 + lg * 4);
    float mx = -3.0e38f;
#pragma unroll
    for (int fk = 0; fk < 4; ++fk)
#pragma unroll
      for (int r = 0; r < 4; ++r) {
        float v = st[fk][fq][r] * 0.17677669529663687f + ((const float*)&bv[fk])[r];
        st[fk][fq][r] = v;
        mx = fmaxf(mx, v);
      }
    mx = fmaxf(mx, __shfl_xor(mx, 16));
    mx = fmaxf(mx, __shfl_xor(mx, 32));
    float sm = 0.0f;
#pragma unroll
    for (int fk = 0; fk < 4; ++fk)
#pragma unroll
      for (int r = 0; r < 4; ++r) {
        float e = __expf(st[fk][fq][r] - mx);
        st[fk][fq][r] = e;
        sm += e;
      }
    sm += __shfl_xor(sm, 16);
    sm += __shfl_xor(sm, 32);
    const float inv = 1.0f / sm;
#pragma unroll
    for (int fk = 0; fk < 4; ++fk)
#pragma unroll
      for (int r = 0; r < 4; ++r) st[fk][fq][r] *= inv;
  }

  // O^T = V^T · P^T ; sigma(g,j)=32kb+16(j>>2)+4g+(j&3) on both operands
  s16x8 va[2][2];
#pragma unroll
  for (int fd = 0; fd < 2; ++fd)
#pragma unroll
    for (int kb = 0; kb < 2; ++kb) {
      short4 v0 = *(const short4*)(Vts + (fd * 16 + lr) * 72 + kb * 32 + lg * 4);
      short4 v1 = *(const short4*)(Vts + (fd * 16 + lr) * 72 + kb * 32 + 16 + lg * 4);
      s16x8 tv;
      tv[0] = v0.x; tv[1] = v0.y; tv[2] = v0.z; tv[3] = v0.w;
      tv[4] = v1.x; tv[5] = v1.y; tv[6] = v1.z; tv[7] = v1.w;
      va[fd][kb] = tv;
    }
  f32x4 ot[2][4];
#pragma unroll
  for (int fd = 0; fd < 2; ++fd)
#pragma unroll
    for (int fq = 0; fq < 4; ++fq) ot[fd][fq] = (f32x4)0.0f;
#pragma unroll
  for (int kb = 0; kb < 2; ++kb)
#pragma unroll
    for (int fq = 0; fq < 4; ++fq) {
      s16x8 pb;
#pragma unroll
      for (int j = 0; j < 8; ++j)
        pb[j] = f2bf(st[2 * kb + (j >> 2)][fq][j & 3]);   // lane-local repack
#pragma unroll
      for (int fd = 0; fd < 2; ++fd)
        ot[fd][fq] = MFMA16(va[fd][kb], pb, ot[fd][fq]);
    }

  // epilogue: stage O [q][d] in Qs (dead), write coalesced 64B rows
#pragma unroll
  for (int fd = 0; fd < 2; ++fd)
#pragma unroll
    for (int fq = 0; fq < 4; ++fq)
#pragma unroll
      for (int r = 0; r < 4; ++r)
        Qs[(fq * 16 + lr) * 40 + fd * 16 + lg * 4 + r] = f2bf(ot[fd][fq][r]);
  short* dst = AO + ((size_t)w * 64 + l) * 384 + h * 32;
  int4 o0 = *(const int4*)(Qs + l * 40);
  int4 o1 = *(const int4*)(Qs + l * 40 + 8);
  int4 o2 = *(const int4*)(Qs + l * 40 + 16);
  int4 o3 = *(const int4*)(Qs + l * 40 + 24);
  *(int4*)(dst)      = o0;
  *(int4*)(dst + 8)  = o1;
  *(int4*)(dst + 16) = o2;
  *(int4*)(dst + 24) = o3;
}

// ---------------- output projection: out = AO(bf16) @ Wo + bo, f32 out --------
// R7-proven BK=64 2-deep counted-vmcnt pipeline.
__global__ __launch_bounds__(256) void proj_kernel(
    const short* __restrict__ AO, const short* __restrict__ WoT,
    const float* __restrict__ bo, float* __restrict__ out)
{
  __shared__ short lds[32768];
  const int bid = blockIdx.x;
  const int wg = (bid & 7) * 294 + (bid >> 3);   // XCD swizzle (2352 = 8*294)
  const int nt = wg % 3, mt = wg / 3;
  const int t = threadIdx.x;
  const int wv = t >> 6, l = t & 63, lr = l & 15, lg = l >> 4;
  const int wm = wv >> 1, wn = wv & 1;

  f32x4 acc[4][4];
#pragma unroll
  for (int fm = 0; fm < 4; ++fm)
#pragma unroll
    for (int fn = 0; fn < 4; ++fn) acc[fm][fn] = (f32x4)0.0f;

  const int srow = wv * 32 + (l >> 3);
  const int cg = (l & 7) ^ (srow & 7);
  const short* Ab = AO  + (size_t)(mt * 128 + srow) * 384 + cg * 8;
  const short* Bb = WoT + (size_t)(nt * 128 + srow) * 384 + cg * 8;

#define STAGE(KS, SEL) do {                                                  \
  _Pragma("unroll")                                                          \
  for (int i_ = 0; i_ < 4; ++i_) {                                           \
    gload_lds16(Ab + i_ * 3072 + (KS) * 64,                                  \
                lds + (SEL) * 16384 + (wv * 4 + i_) * 512);                  \
    gload_lds16(Bb + i_ * 3072 + (KS) * 64,                                  \
                lds + (SEL) * 16384 + 8192 + (wv * 4 + i_) * 512);           \
  } } while (0)

#define COMPUTE(SEL) do {                                                    \
  const short* Acur_ = lds + (SEL) * 16384;                                  \
  const short* Bcur_ = Acur_ + 8192;                                         \
  _Pragma("unroll")                                                          \
  for (int kk = 0; kk < 2; ++kk) {                                           \
    s16x8 af[4], bf[4];                                                      \
    _Pragma("unroll")                                                        \
    for (int f = 0; f < 4; ++f) {                                            \
      const int arow = wm * 64 + f * 16 + lr;                                \
      const int ac = (kk * 4 + lg) ^ (arow & 7);                             \
      af[f] = *(const s16x8*)(Acur_ + arow * 64 + ac * 8);                   \
      const int brow = wn * 64 + f * 16 + lr;                                \
      const int bc = (kk * 4 + lg) ^ (brow & 7);                             \
      bf[f] = *(const s16x8*)(Bcur_ + brow * 64 + bc * 8);                   \
    }                                                                        \
    _Pragma("unroll")                                                        \
    for (int fm = 0; fm < 4; ++fm)                                           \
      _Pragma("unroll")                                                      \
      for (int fn = 0; fn < 4; ++fn)                                         \
        acc[fm][fn] = MFMA16(af[fm], bf[fn], acc[fm][fn]);                   \
  } } while (0)

#define ITER(T, WN) do {                                                     \
  asm volatile("s_waitcnt vmcnt(" #WN ")" ::: "memory");                     \
  __builtin_amdgcn_s_barrier();                                              \
  COMPUTE((T) & 1);                                                          \
  asm volatile("s_waitcnt lgkmcnt(0)" ::: "memory");  /* WAR drain */        \
  __builtin_amdgcn_s_barrier();                                              \
  if ((T) + 2 < 6) STAGE((T) + 2, (T) & 1);                                  \
  } while (0)

  STAGE(0, 0);
  STAGE(1, 1);
  ITER(0, 8); ITER(1, 8); ITER(2, 8); ITER(3, 8); ITER(4, 8); ITER(5, 0);
#undef ITER
#undef COMPUTE
#undef STAGE

#pragma unroll
  for (int fn = 0; fn < 4; ++fn) {
    const int n = nt * 128 + wn * 64 + fn * 16 + lr;
    const float bias = bo[n];
#pragma unroll
    for (int fm = 0; fm < 4; ++fm) {
      const int m0 = mt * 128 + wm * 64 + fm * 16 + lg * 4;
#pragma unroll
      for (int r = 0; r < 4; ++r)
        out[(size_t)(m0 + r) * 384 + n] = acc[fm][fn][r] + bias;
    }
  }
}

extern "C" void kernel_launch(void* const* d_in, const int* in_sizes, int n_in,
                              void* d_out, int out_size, void* d_ws, size_t ws_size,
                              hipStream_t stream)
{
  const float* X    = (const float*)d_in[0];
  const float* Wqkv = (const float*)d_in[1];
  const float* posb = (const float*)d_in[2];
  const float* Wo   = (const float*)d_in[3];
  const float* bo   = (const float*)d_in[4];
  const int*   relp = (const int*)d_in[5];
  float* out = (float*)d_out;

  // workspace carve — ~155.5 MB
  char* ws = (char*)d_ws;
  short* WqkvT = (short*)(ws);                 //   884,736 B
  short* WoT   = (short*)(ws + 884736);        //   294,912 B
  float* biasF = (float*)(ws + 1179648);       //   196,608 B
  short* Xbf   = (short*)(ws + 1376256);       // 77,070,336 B [100352][384]
  short* AO    = (short*)(ws + 78446592);      // 77,070,336 B [100352][384]

  prep_kernel<<<2496, 256, 0, stream>>>(Wqkv, Wo, posb, relp, WqkvT, WoT, biasF);
  xcvt_kernel<<<2048, 256, 0, stream>>>(X, Xbf);
  qkv_attn<<<4704, 256, 0, stream>>>(Xbf, WqkvT, biasF, AO);
  proj_kernel<<<2352, 256, 0, stream>>>(AO, WoT, bo, out);
}

// Round 14
// 232.560 us; speedup vs baseline: 1.7587x; 1.0120x over previous
//
#include <hip/hip_runtime.h>
#include <hip/hip_bf16.h>

typedef float f32x4 __attribute__((ext_vector_type(4)));
typedef short s16x8 __attribute__((ext_vector_type(8)));

#define MFMA16(A,B,C) __builtin_amdgcn_mfma_f32_16x16x32_bf16((A),(B),(C),0,0,0)

// Hardware RNE f32->bf16 (compiler emits v_cvt_pk_bf16_f32 for pairs; the
// old 4-5-op bit-twiddle was ~40% of qkv_attn's VALU budget). Same rounding.
__device__ __forceinline__ short f2bf(float f) {
  return (short)__bfloat16_as_ushort(__float2bfloat16(f));
}

__device__ __forceinline__ void gload_lds16(const void* g, void* l) {
  __builtin_amdgcn_global_load_lds(
      (const __attribute__((address_space(1))) unsigned*)g,
      (__attribute__((address_space(3))) unsigned*)l, 16, 0, 0);
}

// ---------------- prep: transpose weights to bf16[N][K], gather bias table ----
__global__ __launch_bounds__(256) void prep_kernel(
    const float* __restrict__ Wqkv, const float* __restrict__ Wo,
    const float* __restrict__ posb, const int* __restrict__ relp,
    short* __restrict__ WqkvT, short* __restrict__ WoT, float* __restrict__ biasF)
{
  int i = blockIdx.x * 256 + threadIdx.x;
  if (i < 1152 * 384) {
    int n = i / 384, k = i % 384;
    WqkvT[i] = f2bf(Wqkv[k * 1152 + n]);
  } else if (i < 1152 * 384 + 384 * 384) {
    int j = i - 1152 * 384;
    int n = j / 384, k = j % 384;
    WoT[j] = f2bf(Wo[k * 384 + n]);
  } else {
    int j = i - (1152 * 384 + 384 * 384);    // j < 12*64*64 = 49152
    int h = j >> 12, qk = j & 4095;
    biasF[j] = posb[h * 16129 + relp[qk]];
  }
}

// ---------------- X f32 -> bf16 (memory-bound, vectorized) --------------------
__global__ __launch_bounds__(256) void xcvt_kernel(
    const float* __restrict__ X, short* __restrict__ Xbf)
{
  const int n8 = 4816896;                  // 38,535,168 / 8
  for (int i = blockIdx.x * 256 + threadIdx.x; i < n8; i += gridDim.x * 256) {
    float4 a = *(const float4*)(X + (size_t)i * 8);
    float4 b = *(const float4*)(X + (size_t)i * 8 + 4);
    s16x8 p;
    p[0] = f2bf(a.x); p[1] = f2bf(a.y); p[2] = f2bf(a.z); p[3] = f2bf(a.w);
    p[4] = f2bf(b.x); p[5] = f2bf(b.y); p[6] = f2bf(b.z); p[7] = f2bf(b.w);
    *(s16x8*)(Xbf + (size_t)i * 8) = p;
  }
}

// ---------------- fused QKV GEMM + attention (2 heads / block) ----------------
// R12-proven structure, unchanged except f2bf -> hardware cvt.
__global__ __launch_bounds__(256) void qkv_attn(
    const short* __restrict__ Xbf, const short* __restrict__ WqkvT,
    const float* __restrict__ biasF, short* __restrict__ AO)
{
  __shared__ short lds[40960];   // A: sel*8192 | B: 16384 + sel*12288 (shorts)
  const int bid = blockIdx.x;
  const int wg = (bid & 7) * 588 + (bid >> 3);   // XCD swizzle (4704 = 8*588)
  const int hg = wg % 6, mt = wg / 6;
  const int t = threadIdx.x;
  const int wv = t >> 6, l = t & 63, lr = l & 15, lg = l >> 4;
  const int wm = wv >> 1, wn = wv & 1;

  f32x4 acc[4][6];
#pragma unroll
  for (int fm = 0; fm < 4; ++fm)
#pragma unroll
    for (int fn = 0; fn < 6; ++fn) acc[fm][fn] = (f32x4)0.0f;

  const int cgs = (l & 7) ^ (l >> 3);
  const short* AbT = Xbf + (size_t)(mt * 128 + wv * 32 + (l >> 3)) * 384 + cgs * 8;
  const short* BbT[6];
#pragma unroll
  for (int j = 0; j < 6; ++j) {
    const int n0 = wv * 48 + j * 8 + (l >> 3);
    const int hl = n0 / 96, rem = n0 % 96;
    const int p = rem >> 5, d = rem & 31;
    BbT[j] = WqkvT + (size_t)(p * 384 + hg * 64 + hl * 32 + d) * 384 + cgs * 8;
  }

#define STAGE(KS, SEL) do {                                                  \
  _Pragma("unroll")                                                          \
  for (int i_ = 0; i_ < 4; ++i_)                                             \
    gload_lds16(AbT + i_ * 3072 + (KS) * 64,                                 \
                lds + (SEL) * 8192 + (wv * 4 + i_) * 512);                   \
  _Pragma("unroll")                                                          \
  for (int j_ = 0; j_ < 6; ++j_)                                             \
    gload_lds16(BbT[j_] + (KS) * 64,                                         \
                lds + 16384 + (SEL) * 12288 + (wv * 6 + j_) * 512);          \
  } while (0)

#define COMPUTE(SEL) do {                                                    \
  const short* Acur_ = lds + (SEL) * 8192;                                   \
  const short* Bcur_ = lds + 16384 + (SEL) * 12288;                          \
  _Pragma("unroll")                                                          \
  for (int kk = 0; kk < 2; ++kk) {                                           \
    s16x8 af[4], bq[6];                                                      \
    _Pragma("unroll")                                                        \
    for (int f = 0; f < 4; ++f) {                                            \
      const int arow = wm * 64 + f * 16 + lr;                                \
      const int ac = (kk * 4 + lg) ^ (arow & 7);                             \
      af[f] = *(const s16x8*)(Acur_ + arow * 64 + ac * 8);                   \
    }                                                                        \
    _Pragma("unroll")                                                        \
    for (int fn = 0; fn < 6; ++fn) {                                         \
      const int brow = wn * 96 + fn * 16 + lr;                               \
      const int bc = (kk * 4 + lg) ^ (brow & 7);                             \
      bq[fn] = *(const s16x8*)(Bcur_ + brow * 64 + bc * 8);                  \
    }                                                                        \
    _Pragma("unroll")                                                        \
    for (int fm = 0; fm < 4; ++fm)                                           \
      _Pragma("unroll")                                                      \
      for (int fn = 0; fn < 6; ++fn)                                         \
        acc[fm][fn] = MFMA16(af[fm], bq[fn], acc[fm][fn]);                   \
  } } while (0)

#define ITER(T, WN) do {                                                     \
  asm volatile("s_waitcnt vmcnt(" #WN ")" ::: "memory");                     \
  __builtin_amdgcn_s_barrier();                                              \
  COMPUTE((T) & 1);                                                          \
  asm volatile("s_waitcnt lgkmcnt(0)" ::: "memory");  /* WAR drain */        \
  __builtin_amdgcn_s_barrier();                                              \
  if ((T) + 2 < 6) STAGE((T) + 2, (T) & 1);                                  \
  } while (0)

  STAGE(0, 0);
  STAGE(1, 1);
  ITER(0, 10); ITER(1, 10); ITER(2, 10); ITER(3, 10); ITER(4, 10); ITER(5, 0);
#undef ITER
#undef COMPUTE
#undef STAGE

  __syncthreads();       // GEMM LDS dead; reuse for per-wave attn scratch

  // ---- attention (R1/R11-verified path, one (window, head) per wave) ----
  const int w = mt * 2 + wm, h = hg * 2 + wn;
  short* Qs  = lds + wv * 7424;          // [64][40]
  short* Ks  = Qs + 2560;                // [64][40]
  short* Vts = Ks + 2560;                // [32][72]

  // scatter acc -> Q, K, V^T (fn: 0,1=Q 2,3=K 4,5=V; col d=(fn&1)*16+lr)
#pragma unroll
  for (int fm = 0; fm < 4; ++fm) {
#pragma unroll
    for (int fn = 0; fn < 6; ++fn) {
      const int sel = fn >> 1;
      const int d = (fn & 1) * 16 + lr;
      if (sel < 2) {
        short* dst = (sel ? Ks : Qs) + (fm * 16 + lg * 4) * 40 + d;
#pragma unroll
        for (int r = 0; r < 4; ++r) dst[r * 40] = f2bf(acc[fm][fn][r]);
      } else {                           // V stored transposed [d][tok]
        short4 v;
        v.x = f2bf(acc[fm][fn][0]); v.y = f2bf(acc[fm][fn][1]);
        v.z = f2bf(acc[fm][fn][2]); v.w = f2bf(acc[fm][fn][3]);
        *(short4*)(Vts + d * 72 + fm * 16 + lg * 4) = v;
      }
    }
  }

  // S^T = K·Q^T  (rows kt, cols q), K-dim 32
  s16x8 ka[4], qf[4];
#pragma unroll
  for (int f = 0; f < 4; ++f) {
    ka[f] = *(const s16x8*)(Ks + (f * 16 + lr) * 40 + lg * 8);
    qf[f] = *(const s16x8*)(Qs + (f * 16 + lr) * 40 + lg * 8);
  }
  f32x4 st[4][4];
#pragma unroll
  for (int fk = 0; fk < 4; ++fk)
#pragma unroll
    for (int fq = 0; fq < 4; ++fq)
      st[fk][fq] = MFMA16(ka[fk], qf[fq], (f32x4)0.0f);

  // scale + bias + softmax over kt (per q column, per-lane + shfl 16/32)
  const float* bh = biasF + h * 4096;
#pragma unroll
  for (int fq = 0; fq < 4; ++fq) {
    const int q = fq * 16 + lr;
    float4 bv[4];
#pragma unroll
    for (int fk = 0; fk < 4; ++fk)
      bv[fk] = *(const float4*)(bh + q * 64 + fk * 16 + lg * 4);
    float mx = -3.0e38f;
#pragma unroll
    for (int fk = 0; fk < 4; ++fk)
#pragma unroll
      for (int r = 0; r < 4; ++r) {
        float v = st[fk][fq][r] * 0.17677669529663687f + ((const float*)&bv[fk])[r];
        st[fk][fq][r] = v;
        mx = fmaxf(mx, v);
      }
    mx = fmaxf(mx, __shfl_xor(mx, 16));
    mx = fmaxf(mx, __shfl_xor(mx, 32));
    float sm = 0.0f;
#pragma unroll
    for (int fk = 0; fk < 4; ++fk)
#pragma unroll
      for (int r = 0; r < 4; ++r) {
        float e = __expf(st[fk][fq][r] - mx);
        st[fk][fq][r] = e;
        sm += e;
      }
    sm += __shfl_xor(sm, 16);
    sm += __shfl_xor(sm, 32);
    const float inv = 1.0f / sm;
#pragma unroll
    for (int fk = 0; fk < 4; ++fk)
#pragma unroll
      for (int r = 0; r < 4; ++r) st[fk][fq][r] *= inv;
  }

  // O^T = V^T · P^T ; sigma(g,j)=32kb+16(j>>2)+4g+(j&3) on both operands
  s16x8 va[2][2];
#pragma unroll
  for (int fd = 0; fd < 2; ++fd)
#pragma unroll
    for (int kb = 0; kb < 2; ++kb) {
      short4 v0 = *(const short4*)(Vts + (fd * 16 + lr) * 72 + kb * 32 + lg * 4);
      short4 v1 = *(const short4*)(Vts + (fd * 16 + lr) * 72 + kb * 32 + 16 + lg * 4);
      s16x8 tv;
      tv[0] = v0.x; tv[1] = v0.y; tv[2] = v0.z; tv[3] = v0.w;
      tv[4] = v1.x; tv[5] = v1.y; tv[6] = v1.z; tv[7] = v1.w;
      va[fd][kb] = tv;
    }
  f32x4 ot[2][4];
#pragma unroll
  for (int fd = 0; fd < 2; ++fd)
#pragma unroll
    for (int fq = 0; fq < 4; ++fq) ot[fd][fq] = (f32x4)0.0f;
#pragma unroll
  for (int kb = 0; kb < 2; ++kb)
#pragma unroll
    for (int fq = 0; fq < 4; ++fq) {
      s16x8 pb;
#pragma unroll
      for (int j = 0; j < 8; ++j)
        pb[j] = f2bf(st[2 * kb + (j >> 2)][fq][j & 3]);   // lane-local repack
#pragma unroll
      for (int fd = 0; fd < 2; ++fd)
        ot[fd][fq] = MFMA16(va[fd][kb], pb, ot[fd][fq]);
    }

  // epilogue: stage O [q][d] in Qs (dead), write coalesced 64B rows
#pragma unroll
  for (int fd = 0; fd < 2; ++fd)
#pragma unroll
    for (int fq = 0; fq < 4; ++fq)
#pragma unroll
      for (int r = 0; r < 4; ++r)
        Qs[(fq * 16 + lr) * 40 + fd * 16 + lg * 4 + r] = f2bf(ot[fd][fq][r]);
  short* dst = AO + ((size_t)w * 64 + l) * 384 + h * 32;
  int4 o0 = *(const int4*)(Qs + l * 40);
  int4 o1 = *(const int4*)(Qs + l * 40 + 8);
  int4 o2 = *(const int4*)(Qs + l * 40 + 16);
  int4 o3 = *(const int4*)(Qs + l * 40 + 24);
  *(int4*)(dst)      = o0;
  *(int4*)(dst + 8)  = o1;
  *(int4*)(dst + 16) = o2;
  *(int4*)(dst + 24) = o3;
}

// ---------------- output projection: out = AO(bf16) @ Wo + bo, f32 out --------
// R7-proven BK=64 2-deep counted-vmcnt pipeline.
__global__ __launch_bounds__(256) void proj_kernel(
    const short* __restrict__ AO, const short* __restrict__ WoT,
    const float* __restrict__ bo, float* __restrict__ out)
{
  __shared__ short lds[32768];
  const int bid = blockIdx.x;
  const int wg = (bid & 7) * 294 + (bid >> 3);   // XCD swizzle (2352 = 8*294)
  const int nt = wg % 3, mt = wg / 3;
  const int t = threadIdx.x;
  const int wv = t >> 6, l = t & 63, lr = l & 15, lg = l >> 4;
  const int wm = wv >> 1, wn = wv & 1;

  f32x4 acc[4][4];
#pragma unroll
  for (int fm = 0; fm < 4; ++fm)
#pragma unroll
    for (int fn = 0; fn < 4; ++fn) acc[fm][fn] = (f32x4)0.0f;

  const int srow = wv * 32 + (l >> 3);
  const int cg = (l & 7) ^ (srow & 7);
  const short* Ab = AO  + (size_t)(mt * 128 + srow) * 384 + cg * 8;
  const short* Bb = WoT + (size_t)(nt * 128 + srow) * 384 + cg * 8;

#define STAGE(KS, SEL) do {                                                  \
  _Pragma("unroll")                                                          \
  for (int i_ = 0; i_ < 4; ++i_) {                                           \
    gload_lds16(Ab + i_ * 3072 + (KS) * 64,                                  \
                lds + (SEL) * 16384 + (wv * 4 + i_) * 512);                  \
    gload_lds16(Bb + i_ * 3072 + (KS) * 64,                                  \
                lds + (SEL) * 16384 + 8192 + (wv * 4 + i_) * 512);           \
  } } while (0)

#define COMPUTE(SEL) do {                                                    \
  const short* Acur_ = lds + (SEL) * 16384;                                  \
  const short* Bcur_ = Acur_ + 8192;                                         \
  _Pragma("unroll")                                                          \
  for (int kk = 0; kk < 2; ++kk) {                                           \
    s16x8 af[4], bf[4];                                                      \
    _Pragma("unroll")                                                        \
    for (int f = 0; f < 4; ++f) {                                            \
      const int arow = wm * 64 + f * 16 + lr;                                \
      const int ac = (kk * 4 + lg) ^ (arow & 7);                             \
      af[f] = *(const s16x8*)(Acur_ + arow * 64 + ac * 8);                   \
      const int brow = wn * 64 + f * 16 + lr;                                \
      const int bc = (kk * 4 + lg) ^ (brow & 7);                             \
      bf[f] = *(const s16x8*)(Bcur_ + brow * 64 + bc * 8);                   \
    }                                                                        \
    _Pragma("unroll")                                                        \
    for (int fm = 0; fm < 4; ++fm)                                           \
      _Pragma("unroll")                                                      \
      for (int fn = 0; fn < 4; ++fn)                                         \
        acc[fm][fn] = MFMA16(af[fm], bf[fn], acc[fm][fn]);                   \
  } } while (0)

#define ITER(T, WN) do {                                                     \
  asm volatile("s_waitcnt vmcnt(" #WN ")" ::: "memory");                     \
  __builtin_amdgcn_s_barrier();                                              \
  COMPUTE((T) & 1);                                                          \
  asm volatile("s_waitcnt lgkmcnt(0)" ::: "memory");  /* WAR drain */        \
  __builtin_amdgcn_s_barrier();                                              \
  if ((T) + 2 < 6) STAGE((T) + 2, (T) & 1);                                  \
  } while (0)

  STAGE(0, 0);
  STAGE(1, 1);
  ITER(0, 8); ITER(1, 8); ITER(2, 8); ITER(3, 8); ITER(4, 8); ITER(5, 0);
#undef ITER
#undef COMPUTE
#undef STAGE

#pragma unroll
  for (int fn = 0; fn < 4; ++fn) {
    const int n = nt * 128 + wn * 64 + fn * 16 + lr;
    const float bias = bo[n];
#pragma unroll
    for (int fm = 0; fm < 4; ++fm) {
      const int m0 = mt * 128 + wm * 64 + fm * 16 + lg * 4;
#pragma unroll
      for (int r = 0; r < 4; ++r)
        out[(size_t)(m0 + r) * 384 + n] = acc[fm][fn][r] + bias;
    }
  }
}

extern "C" void kernel_launch(void* const* d_in, const int* in_sizes, int n_in,
                              void* d_out, int out_size, void* d_ws, size_t ws_size,
                              hipStream_t stream)
{
  const float* X    = (const float*)d_in[0];
  const float* Wqkv = (const float*)d_in[1];
  const float* posb = (const float*)d_in[2];
  const float* Wo   = (const float*)d_in[3];
  const float* bo   = (const float*)d_in[4];
  const int*   relp = (const int*)d_in[5];
  float* out = (float*)d_out;

  // workspace carve — ~155.5 MB
  char* ws = (char*)d_ws;
  short* WqkvT = (short*)(ws);                 //   884,736 B
  short* WoT   = (short*)(ws + 884736);        //   294,912 B
  float* biasF = (float*)(ws + 1179648);       //   196,608 B
  short* Xbf   = (short*)(ws + 1376256);       // 77,070,336 B [100352][384]
  short* AO    = (short*)(ws + 78446592);      // 77,070,336 B [100352][384]

  prep_kernel<<<2496, 256, 0, stream>>>(Wqkv, Wo, posb, relp, WqkvT, WoT, biasF);
  xcvt_kernel<<<2048, 256, 0, stream>>>(X, Xbf);
  qkv_attn<<<4704, 256, 0, stream>>>(Xbf, WqkvT, biasF, AO);
  proj_kernel<<<2352, 256, 0, stream>>>(AO, WoT, bo, out);
}